// Round 7
// baseline (74.722 us; speedup 1.0000x reference)
//
#include <hip/hip_runtime.h>

// B=256, N=512 cells, G=117 genes, CH=25 conv channels.
// Conv as MFMA with REGISTER handoff to the regression matmul (no K-loop
// barriers, no A2 LDS round-trip):
//   per wave (ct=cells 32-group, cg=gene 64-half), per jt (32 j's):
//     o = W_big^T(32j x 64i) @ img(64i x 32cells)      [4 MFMA, 32x32x16]
//     relu -> v_cvt_pk_bf16_f32 (8) -> permlane32_swap (4)  => 2 A-frags
//     acc_t += A2frag @ W_reg^T(kstep, tile t)         [4 MFMA]
//   mm1 D-frag lane->col=cell matches mm2 A-frag lane->row=cell; the swap
//   exchanges j{4-7}<->j{8-11} halves across hh (one swap fills 2 words).
// Block = 128 cells x 128 genes, 512 thr = 8 waves (4 ct x 2 cg); conv
// duplicated 2x per ct (cg pair) - MFMA issue is cheap.
// Epilogue: 2 passes of C[64][128] f32 LDS -> coalesced cell+out1 streams,
// spot partials from LDS. 6 barriers total, none in the K loop.

typedef __attribute__((ext_vector_type(16))) float f32x16;
typedef __attribute__((ext_vector_type(8))) short short8;
typedef __attribute__((ext_vector_type(2))) unsigned int uint2v;
typedef __attribute__((ext_vector_type(4))) unsigned int uint4v;

#define WB_OFF    0          // 163840 B : W_reg bf16 B-frags [40 ksteps][4 t][64][8]
#define WBIG_OFF  163840     // 81920 B  : W_big^T bf16 A-frags [20 jt][4 s][64][8]
#define GLOB_OFF  245760     // 1024 B   : glob[256]
#define SPOT_OFF  246784     // 512 KB   : [256][4][128] f32 partials

#define SPOT_OUT_OFF 0
#define CELL_OUT_OFF 29952
#define OUT1_OUT_OFF 15365376

__device__ __forceinline__ unsigned short f2bf(float x) {
  unsigned int u = __builtin_bit_cast(unsigned int, x);
  u = (u + 0x7FFFu + ((u >> 16) & 1u)) >> 16;   // RNE
  return (unsigned short)u;
}

__device__ __forceinline__ unsigned int cvt_pk_bf16(float lo, float hi) {
  unsigned int w;
  asm("v_cvt_pk_bf16_f32 %0, %1, %2" : "=v"(w) : "v"(lo), "v"(hi));
  return w;
}

// blocks 0..255: glob ; 256..335: wbig (jt x s) ; 336..495: wb (sg x wc)
__global__ __launch_bounds__(128) void prep_kernel(
    const float* __restrict__ spot_images, const float* __restrict__ W_patch,
    const float* __restrict__ b_patch, const float* __restrict__ W_glob,
    const float* __restrict__ b_glob, const float* __restrict__ W_reg,
    const float* __restrict__ W_emph, const float* __restrict__ b_emph,
    unsigned short* __restrict__ wb, unsigned short* __restrict__ wbig,
    float* __restrict__ glob) {
  int bid = blockIdx.x;
  int tid = threadIdx.x;
  if (bid < 256) {
    __shared__ float red[75];
    if (tid < 75) {
      int token = tid / 3;
      int chan = tid - token * 3;
      int ty = token / 5, tx = token - ty * 5;
      const float* img = spot_images + bid * 784 + (ty * 5) * 28 + tx * 5;
      float a = 0.f;
      #pragma unroll
      for (int i = 0; i < 5; ++i)
        #pragma unroll
        for (int j = 0; j < 5; ++j)
          a = fmaf(img[i * 28 + j], W_patch[chan * 25 + i * 5 + j], a);
      a += b_patch[chan];
      red[tid] = a * W_glob[tid];
    }
    __syncthreads();
    if (tid == 0) {
      float s = b_glob[0];
      for (int k = 0; k < 75; ++k) s += red[k];
      glob[bid] = (s > 0.f) ? s : expm1f(s);
    }
  } else if (bid < 336) {
    int idx = bid - 256;               // jt*4 + s
    int jt = idx >> 2, s = idx & 3;
    if (tid < 64) {
      int j = jt * 32 + (tid & 31);
      int h = tid >> 5;
      unsigned short hv[8];
      #pragma unroll
      for (int jj = 0; jj < 8; ++jj) {
        int i = s * 16 + h * 8 + jj;
        float val = 0.f;
        if (j < 625) {
          int ch = j / 25, p = j % 25;
          int oy = p / 5, ox = p - oy * 5;
          if (i < 49) {
            int iy = i / 7, ix = i - iy * 7;
            int ky = iy - oy, kx = ix - ox;
            if (ky >= 0 && ky < 3 && kx >= 0 && kx < 3)
              val = W_emph[ch * 9 + ky * 3 + kx];
          } else if (i == 49) {
            val = b_emph[ch];
          }
        }
        hv[jj] = f2bf(val);
      }
      unsigned int u[4];
      #pragma unroll
      for (int k = 0; k < 4; ++k)
        u[k] = (unsigned int)hv[2 * k] | ((unsigned int)hv[2 * k + 1] << 16);
      ((uint4*)wbig)[idx * 64 + tid] = make_uint4(u[0], u[1], u[2], u[3]);
    }
  } else {
    int idx = bid - 336;               // sg*4 + wc
    int sg = idx >> 2, wcp = idx & 3;
    if (tid < 64) {
      int g = wcp * 32 + (tid & 31);
      int h = tid >> 5;
      unsigned short hv[8];
      #pragma unroll
      for (int jj = 0; jj < 8; ++jj) {
        int k = sg * 16 + h * 8 + jj;
        float val = (g < 117 && k < 625) ? W_reg[g * 625 + k] : 0.f;
        hv[jj] = f2bf(val);
      }
      unsigned int u[4];
      #pragma unroll
      for (int k = 0; k < 4; ++k)
        u[k] = (unsigned int)hv[2 * k] | ((unsigned int)hv[2 * k + 1] << 16);
      ((uint4*)wb)[idx * 64 + tid] = make_uint4(u[0], u[1], u[2], u[3]);
    }
  }
}

// One block = (batch b, 128-cell quarter). 512 threads = 8 waves (4 ct x 2 cg).
__global__ __launch_bounds__(512, 4) void main_kernel(
    const float* __restrict__ images, const float* __restrict__ b_reg,
    const unsigned short* __restrict__ wb, const unsigned short* __restrict__ wbig,
    const float* __restrict__ glob, float* __restrict__ out,
    float* __restrict__ spotp) {
  __shared__ char smem[34816];
  unsigned short* imgbs = (unsigned short*)smem;   // 16384 B [8 kc][128 cell][8]
  float* C = (float*)smem;                         // 32768 B [64][128] (epilogue)
  float* red = (float*)(smem + 32768);             // 2048 B [4][128]
  int tid = threadIdx.x;
  int bid = blockIdx.x;
  int b = bid >> 2, quarter = bid & 3;
  int n0 = quarter * 128;

  // ---- stage img -> bf16 chunk-major LDS (i=49 -> 1.0 bias column) ----
  #pragma unroll
  for (int it = 0; it < 2; ++it) {
    int u = it * 512 + tid;
    int cell = u & 127, kc = u >> 7;
    const float* src = images + (size_t)(b * 512 + n0 + cell) * 49 + kc * 8;
    float v[8];
    #pragma unroll
    for (int j = 0; j < 8; ++j) v[j] = 0.f;
    if (kc < 6) {
      #pragma unroll
      for (int j = 0; j < 8; ++j) v[j] = src[j];
    } else if (kc == 6) {
      v[0] = src[0];
      v[1] = 1.0f;
    }
    unsigned int uu[4];
    #pragma unroll
    for (int k = 0; k < 4; ++k) uu[k] = cvt_pk_bf16(v[2 * k], v[2 * k + 1]);
    ((uint4*)imgbs)[kc * 128 + cell] = make_uint4(uu[0], uu[1], uu[2], uu[3]);
  }
  __syncthreads();

  int l = tid & 63;
  int wu = __builtin_amdgcn_readfirstlane(tid >> 6);   // 0..7
  int ct = wu >> 1, cg = wu & 1;    // cells ct*32.., genes cg*64..
  int m = l & 31, hh = l >> 5;
  const short8* imgb8 = (const short8*)imgbs;
  const short8* wb8 = (const short8*)wb;
  const short8* wbig8 = (const short8*)wbig;

  // persistent img B-frags (s = 0..3), 16 VGPR
  short8 bi0 = imgb8[(0 + hh) * 128 + ct * 32 + m];
  short8 bi1 = imgb8[(2 + hh) * 128 + ct * 32 + m];
  short8 bi2 = imgb8[(4 + hh) * 128 + ct * 32 + m];
  short8 bi3 = imgb8[(6 + hh) * 128 + ct * 32 + m];

  f32x16 acc0, acc1;
  #pragma unroll
  for (int i = 0; i < 16; ++i) { acc0[i] = 0.f; acc1[i] = 0.f; }

  for (int jt = 0; jt < 20; ++jt) {
    // W_big A-frags for this jt (all waves read the same - L2 resident)
    int ab = jt * 256 + l;
    short8 a0 = wbig8[ab];
    short8 a1 = wbig8[ab + 64];
    short8 a2 = wbig8[ab + 128];
    short8 a3 = wbig8[ab + 192];
    // W_reg B-frags: ksteps 2jt, 2jt+1; tiles 2cg, 2cg+1
    int kb = (jt * 8 + cg * 2) * 64 + l;
    short8 w00 = wb8[kb];
    short8 w01 = wb8[kb + 64];
    short8 w10 = wb8[kb + 256];
    short8 w11 = wb8[kb + 320];

    // mm1: conv for 32 cells x 32 j
    f32x16 o;
    #pragma unroll
    for (int i = 0; i < 16; ++i) o[i] = 0.f;
    o = __builtin_amdgcn_mfma_f32_32x32x16_bf16(a0, bi0, o, 0, 0, 0);
    o = __builtin_amdgcn_mfma_f32_32x32x16_bf16(a1, bi1, o, 0, 0, 0);
    o = __builtin_amdgcn_mfma_f32_32x32x16_bf16(a2, bi2, o, 0, 0, 0);
    o = __builtin_amdgcn_mfma_f32_32x32x16_bf16(a3, bi3, o, 0, 0, 0);

    // relu + pack to bf16 words; W[q] = j(pair) per D layout
    unsigned int W[8];
    #pragma unroll
    for (int q = 0; q < 8; ++q)
      W[q] = cvt_pk_bf16(fmaxf(o[2 * q], 0.f), fmaxf(o[2 * q + 1], 0.f));
    // hh-half exchange: one swap fills two A-frag words
    uint2v s02 = __builtin_amdgcn_permlane32_swap(W[0], W[2], false, false);
    uint2v s13 = __builtin_amdgcn_permlane32_swap(W[1], W[3], false, false);
    uint2v s46 = __builtin_amdgcn_permlane32_swap(W[4], W[6], false, false);
    uint2v s57 = __builtin_amdgcn_permlane32_swap(W[5], W[7], false, false);
    uint4v f0 = {s02[0], s13[0], s02[1], s13[1]};
    uint4v f1 = {s46[0], s57[0], s46[1], s57[1]};
    short8 af0 = __builtin_bit_cast(short8, f0);
    short8 af1 = __builtin_bit_cast(short8, f1);

    // mm2: acc += A2(32cells x 32j) @ W_reg^T(32j x 64genes)
    acc0 = __builtin_amdgcn_mfma_f32_32x32x16_bf16(af0, w00, acc0, 0, 0, 0);
    acc1 = __builtin_amdgcn_mfma_f32_32x32x16_bf16(af0, w01, acc1, 0, 0, 0);
    acc0 = __builtin_amdgcn_mfma_f32_32x32x16_bf16(af1, w10, acc0, 0, 0, 0);
    acc1 = __builtin_amdgcn_mfma_f32_32x32x16_bf16(af1, w11, acc1, 0, 0, 0);
  }

  // ---- epilogue: 2 passes of 64 cells through C[64][128] ----
  float gb = glob[b];
  float part = 0.f;
  size_t rowbase = (size_t)(b * 512 + n0);
  #pragma unroll
  for (int p = 0; p < 2; ++p) {
    if ((ct >> 1) == p) {
      #pragma unroll
      for (int t = 0; t < 2; ++t) {
        int g = (cg * 2 + t) * 32 + m;
        float br = (g < 117) ? b_reg[g] : 0.f;
        f32x16 A = t ? acc1 : acc0;
        #pragma unroll
        for (int reg = 0; reg < 16; ++reg) {
          int n = (ct & 1) * 32 + (reg & 3) + 8 * (reg >> 2) + 4 * hh;
          C[n * 128 + g] = fmaxf(A[reg] + br + gb, 0.f);
        }
      }
    }
    __syncthreads();
    // coalesced streams: cell chunk (29952 B) + out1 (glob bcast)
    float* cellchunk = out + CELL_OUT_OFF + (rowbase + p * 64) * 117;
    #pragma unroll
    for (int i = 0; i < 15; ++i) {
      int idx = i * 512 + tid;
      if (idx < 7488) {
        int n = idx / 117;
        int gg = idx - n * 117;
        cellchunk[idx] = C[n * 128 + gg];
      }
    }
    float4 gv = make_float4(gb, gb, gb, gb);
    float4* o1v = (float4*)(out + OUT1_OUT_OFF + (rowbase + p * 64) * 117);
    #pragma unroll
    for (int i = 0; i < 4; ++i) {
      int idx = i * 512 + tid;
      if (idx < 1872) o1v[idx] = gv;
    }
    // spot partials for this pass
    {
      int grp = tid >> 7, t = tid & 127;
      float s = 0.f;
      #pragma unroll
      for (int n = 0; n < 16; ++n) s += C[(grp * 16 + n) * 128 + t];
      red[grp * 128 + t] = s;
    }
    __syncthreads();
    if (tid < 128)
      part += red[tid] + red[128 + tid] + red[256 + tid] + red[384 + tid];
    if (p == 0) __syncthreads();   // WAR: C and red rewritten in pass 1
  }
  if (tid < 128)
    spotp[(size_t)(b * 4 + quarter) * 128 + tid] = part;
}

// spot[b][g] = sum of 4 quarter partials
__global__ __launch_bounds__(256) void spot_reduce(
    const float* __restrict__ spotp, float* __restrict__ out) {
  int idx = blockIdx.x * 256 + threadIdx.x;   // exactly 117*256 = 29952
  int b = idx / 117;
  int g = idx - b * 117;
  float s = 0.f;
  #pragma unroll
  for (int t = 0; t < 4; ++t) s += spotp[(size_t)(b * 4 + t) * 128 + g];
  out[SPOT_OUT_OFF + idx] = s;
}

extern "C" void kernel_launch(void* const* d_in, const int* in_sizes, int n_in,
                              void* d_out, int out_size, void* d_ws, size_t ws_size,
                              hipStream_t stream) {
  const float* images      = (const float*)d_in[0];
  const float* spot_images = (const float*)d_in[1];
  // d_in[2] = gene_expression (unused by the reference)
  const float* W_emph = (const float*)d_in[3];
  const float* b_emph = (const float*)d_in[4];
  const float* W_reg  = (const float*)d_in[5];
  const float* b_reg  = (const float*)d_in[6];
  const float* W_patch = (const float*)d_in[7];
  const float* b_patch = (const float*)d_in[8];
  const float* W_glob  = (const float*)d_in[9];
  const float* b_glob  = (const float*)d_in[10];
  float* out = (float*)d_out;

  unsigned short* wb   = (unsigned short*)((char*)d_ws + WB_OFF);
  unsigned short* wbig = (unsigned short*)((char*)d_ws + WBIG_OFF);
  float* glob  = (float*)((char*)d_ws + GLOB_OFF);
  float* spotp = (float*)((char*)d_ws + SPOT_OFF);

  prep_kernel<<<496, 128, 0, stream>>>(spot_images, W_patch, b_patch, W_glob,
                                       b_glob, W_reg, W_emph, b_emph, wb, wbig,
                                       glob);
  main_kernel<<<1024, 512, 0, stream>>>(images, b_reg, wb, wbig, glob, out,
                                        spotp);
  spot_reduce<<<117, 256, 0, stream>>>(spotp, out);
}

// Round 8
// 61.871 us; speedup vs baseline: 1.2077x; 1.2077x over previous
//
#include <hip/hip_runtime.h>

// B=256, N=512 cells, G=117 genes, CH=25 conv channels.
// Conv as MFMA with REGISTER handoff to the regression matmul:
//   per wave (ct = 32-cell group), per jt (32 j's):
//     o = W_big^T(32j x 64i) @ img(64i x 32cells)      [4 MFMA 32x32x16]
//     relu -> v_cvt_pk_bf16_f32 (8) -> permlane32_swap (4) => af0, af1
//     acc_q += af @ W_reg^T(kstep, gene quad q)        [8 MFMA]
//   Conv computed EXACTLY once (wave owns all 128 genes for its 32 cells).
// Block = 256 cells (half batch) x 128 genes, 512 thr = 8 waves = 8 ct groups.
// No barriers in the K loop. Epilogue: 4 passes of C[64][128] f32 LDS ->
// coalesced cell + out1 streams + spot partials (stores spread over passes).

typedef __attribute__((ext_vector_type(16))) float f32x16;
typedef __attribute__((ext_vector_type(8))) short short8;
typedef __attribute__((ext_vector_type(2))) unsigned int uint2v;
typedef __attribute__((ext_vector_type(4))) unsigned int uint4v;

#define WB_OFF    0          // 163840 B : W_reg bf16 B-frags [40 ksteps][4 q][64][8]
#define WBIG_OFF  163840     // 81920 B  : W_big^T bf16 A-frags [20 jt][4 s][64][8]
#define GLOB_OFF  245760     // 1024 B   : glob[256]
#define SPOT_OFF  246784     // 256 KB   : [256][2][128] f32 partials

#define SPOT_OUT_OFF 0
#define CELL_OUT_OFF 29952
#define OUT1_OUT_OFF 15365376

__device__ __forceinline__ unsigned short f2bf(float x) {
  unsigned int u = __builtin_bit_cast(unsigned int, x);
  u = (u + 0x7FFFu + ((u >> 16) & 1u)) >> 16;   // RNE
  return (unsigned short)u;
}

__device__ __forceinline__ unsigned int cvt_pk_bf16(float lo, float hi) {
  unsigned int w;
  asm("v_cvt_pk_bf16_f32 %0, %1, %2" : "=v"(w) : "v"(lo), "v"(hi));
  return w;
}

// blocks 0..255: glob ; 256..335: wbig (jt x s) ; 336..495: wb (sg x q)
__global__ __launch_bounds__(128) void prep_kernel(
    const float* __restrict__ spot_images, const float* __restrict__ W_patch,
    const float* __restrict__ b_patch, const float* __restrict__ W_glob,
    const float* __restrict__ b_glob, const float* __restrict__ W_reg,
    const float* __restrict__ W_emph, const float* __restrict__ b_emph,
    unsigned short* __restrict__ wb, unsigned short* __restrict__ wbig,
    float* __restrict__ glob) {
  int bid = blockIdx.x;
  int tid = threadIdx.x;
  if (bid < 256) {
    __shared__ float red[75];
    if (tid < 75) {
      int token = tid / 3;
      int chan = tid - token * 3;
      int ty = token / 5, tx = token - ty * 5;
      const float* img = spot_images + bid * 784 + (ty * 5) * 28 + tx * 5;
      float a = 0.f;
      #pragma unroll
      for (int i = 0; i < 5; ++i)
        #pragma unroll
        for (int j = 0; j < 5; ++j)
          a = fmaf(img[i * 28 + j], W_patch[chan * 25 + i * 5 + j], a);
      a += b_patch[chan];
      red[tid] = a * W_glob[tid];
    }
    __syncthreads();
    if (tid == 0) {
      float s = b_glob[0];
      for (int k = 0; k < 75; ++k) s += red[k];
      glob[bid] = (s > 0.f) ? s : expm1f(s);
    }
  } else if (bid < 336) {
    int idx = bid - 256;               // jt*4 + s
    int jt = idx >> 2, s = idx & 3;
    if (tid < 64) {
      int j = jt * 32 + (tid & 31);
      int h = tid >> 5;
      unsigned short hv[8];
      #pragma unroll
      for (int jj = 0; jj < 8; ++jj) {
        int i = s * 16 + h * 8 + jj;
        float val = 0.f;
        if (j < 625) {
          int ch = j / 25, p = j % 25;
          int oy = p / 5, ox = p - oy * 5;
          if (i < 49) {
            int iy = i / 7, ix = i - iy * 7;
            int ky = iy - oy, kx = ix - ox;
            if (ky >= 0 && ky < 3 && kx >= 0 && kx < 3)
              val = W_emph[ch * 9 + ky * 3 + kx];
          } else if (i == 49) {
            val = b_emph[ch];
          }
        }
        hv[jj] = f2bf(val);
      }
      unsigned int u[4];
      #pragma unroll
      for (int k = 0; k < 4; ++k)
        u[k] = (unsigned int)hv[2 * k] | ((unsigned int)hv[2 * k + 1] << 16);
      ((uint4*)wbig)[idx * 64 + tid] = make_uint4(u[0], u[1], u[2], u[3]);
    }
  } else {
    int idx = bid - 336;               // sg*4 + q
    int sg = idx >> 2, wcp = idx & 3;
    if (tid < 64) {
      int g = wcp * 32 + (tid & 31);
      int h = tid >> 5;
      unsigned short hv[8];
      #pragma unroll
      for (int jj = 0; jj < 8; ++jj) {
        int k = sg * 16 + h * 8 + jj;
        float val = (g < 117 && k < 625) ? W_reg[g * 625 + k] : 0.f;
        hv[jj] = f2bf(val);
      }
      unsigned int u[4];
      #pragma unroll
      for (int k = 0; k < 4; ++k)
        u[k] = (unsigned int)hv[2 * k] | ((unsigned int)hv[2 * k + 1] << 16);
      ((uint4*)wb)[idx * 64 + tid] = make_uint4(u[0], u[1], u[2], u[3]);
    }
  }
}

// One block = (batch b, 256-cell half). 512 threads = 8 waves (ct = cell group).
__global__ __launch_bounds__(512, 4) void main_kernel(
    const float* __restrict__ images, const float* __restrict__ b_reg,
    const unsigned short* __restrict__ wb, const unsigned short* __restrict__ wbig,
    const float* __restrict__ glob, float* __restrict__ out,
    float* __restrict__ spotp) {
  __shared__ char smem[34816];
  unsigned short* imgbs = (unsigned short*)smem;   // 32768 B [8 kc][256 cell][8]
  float* C = (float*)smem;                         // 32768 B [64][128] (epilogue)
  float* red = (float*)(smem + 32768);             // 2048 B [4][128]
  int tid = threadIdx.x;
  int bid = blockIdx.x;
  int b = bid >> 1, half = bid & 1;
  int n0 = half * 256;

  // ---- stage img -> bf16 chunk-major LDS (i=49 -> 1.0 bias column) ----
  #pragma unroll
  for (int it = 0; it < 4; ++it) {
    int u = it * 512 + tid;
    int cell = u & 255, kc = u >> 8;
    const float* src = images + (size_t)(b * 512 + n0 + cell) * 49 + kc * 8;
    float v[8];
    #pragma unroll
    for (int j = 0; j < 8; ++j) v[j] = 0.f;
    if (kc < 6) {
      #pragma unroll
      for (int j = 0; j < 8; ++j) v[j] = src[j];
    } else if (kc == 6) {
      v[0] = src[0];
      v[1] = 1.0f;
    }
    unsigned int uu[4];
    #pragma unroll
    for (int k = 0; k < 4; ++k) uu[k] = cvt_pk_bf16(v[2 * k], v[2 * k + 1]);
    ((uint4*)imgbs)[kc * 256 + cell] = make_uint4(uu[0], uu[1], uu[2], uu[3]);
  }
  __syncthreads();

  int l = tid & 63;
  int ct = __builtin_amdgcn_readfirstlane(tid >> 6);   // 0..7 cell group
  int m = l & 31, hh = l >> 5;
  const short8* imgb8 = (const short8*)imgbs;
  const short8* wb8 = (const short8*)wb;
  const short8* wbig8 = (const short8*)wbig;

  // persistent img B-frags (s = 0..3), 16 VGPR
  short8 bi0 = imgb8[(0 + hh) * 256 + ct * 32 + m];
  short8 bi1 = imgb8[(2 + hh) * 256 + ct * 32 + m];
  short8 bi2 = imgb8[(4 + hh) * 256 + ct * 32 + m];
  short8 bi3 = imgb8[(6 + hh) * 256 + ct * 32 + m];

  f32x16 acc0, acc1, acc2, acc3;
  #pragma unroll
  for (int i = 0; i < 16; ++i) {
    acc0[i] = 0.f; acc1[i] = 0.f; acc2[i] = 0.f; acc3[i] = 0.f;
  }

  for (int jt = 0; jt < 20; ++jt) {
    // W_big A-frags for this jt
    int ab = jt * 256 + l;
    short8 a0 = wbig8[ab];
    short8 a1 = wbig8[ab + 64];
    short8 a2 = wbig8[ab + 128];
    short8 a3 = wbig8[ab + 192];

    // mm1: conv for 32 cells x 32 j (once!)
    f32x16 o;
    #pragma unroll
    for (int i = 0; i < 16; ++i) o[i] = 0.f;
    o = __builtin_amdgcn_mfma_f32_32x32x16_bf16(a0, bi0, o, 0, 0, 0);
    o = __builtin_amdgcn_mfma_f32_32x32x16_bf16(a1, bi1, o, 0, 0, 0);
    o = __builtin_amdgcn_mfma_f32_32x32x16_bf16(a2, bi2, o, 0, 0, 0);
    o = __builtin_amdgcn_mfma_f32_32x32x16_bf16(a3, bi3, o, 0, 0, 0);

    // relu + pack to bf16; hh-half exchange (one swap fills 2 words)
    unsigned int W[8];
    #pragma unroll
    for (int q = 0; q < 8; ++q)
      W[q] = cvt_pk_bf16(fmaxf(o[2 * q], 0.f), fmaxf(o[2 * q + 1], 0.f));
    uint2v s02 = __builtin_amdgcn_permlane32_swap(W[0], W[2], false, false);
    uint2v s13 = __builtin_amdgcn_permlane32_swap(W[1], W[3], false, false);
    uint2v s46 = __builtin_amdgcn_permlane32_swap(W[4], W[6], false, false);
    uint2v s57 = __builtin_amdgcn_permlane32_swap(W[5], W[7], false, false);
    uint4v f0 = {s02[0], s13[0], s02[1], s13[1]};
    uint4v f1 = {s46[0], s57[0], s46[1], s57[1]};
    short8 af0 = __builtin_bit_cast(short8, f0);
    short8 af1 = __builtin_bit_cast(short8, f1);

    // mm2: all 4 gene quads, ksteps 2jt (af0) and 2jt+1 (af1)
    int kb = jt * 512 + l;
    acc0 = __builtin_amdgcn_mfma_f32_32x32x16_bf16(af0, wb8[kb], acc0, 0, 0, 0);
    acc1 = __builtin_amdgcn_mfma_f32_32x32x16_bf16(af0, wb8[kb + 64], acc1, 0, 0, 0);
    acc2 = __builtin_amdgcn_mfma_f32_32x32x16_bf16(af0, wb8[kb + 128], acc2, 0, 0, 0);
    acc3 = __builtin_amdgcn_mfma_f32_32x32x16_bf16(af0, wb8[kb + 192], acc3, 0, 0, 0);
    acc0 = __builtin_amdgcn_mfma_f32_32x32x16_bf16(af1, wb8[kb + 256], acc0, 0, 0, 0);
    acc1 = __builtin_amdgcn_mfma_f32_32x32x16_bf16(af1, wb8[kb + 320], acc1, 0, 0, 0);
    acc2 = __builtin_amdgcn_mfma_f32_32x32x16_bf16(af1, wb8[kb + 384], acc2, 0, 0, 0);
    acc3 = __builtin_amdgcn_mfma_f32_32x32x16_bf16(af1, wb8[kb + 448], acc3, 0, 0, 0);
  }
  __syncthreads();   // all bi/img reads done before C aliases imgbs

  // ---- epilogue: 4 passes of 64 cells through C[64][128] ----
  float gb = glob[b];
  float part = 0.f;
  size_t rowbase = (size_t)(b * 512 + n0);
  #pragma unroll
  for (int p = 0; p < 4; ++p) {
    if ((ct >> 1) == p) {
      int nb = (ct & 1) * 32;
      #define EPI(Q, ACC)                                                  \
        {                                                                  \
          int g = (Q)*32 + m;                                              \
          float br = (g < 117) ? b_reg[g] : 0.f;                           \
          _Pragma("unroll")                                                \
          for (int reg = 0; reg < 16; ++reg) {                             \
            int n = nb + (reg & 3) + 8 * (reg >> 2) + 4 * hh;              \
            C[n * 128 + g] = fmaxf(ACC[reg] + br + gb, 0.f);               \
          }                                                                \
        }
      EPI(0, acc0) EPI(1, acc1) EPI(2, acc2) EPI(3, acc3)
      #undef EPI
    }
    __syncthreads();
    // coalesced streams: cell chunk (29952 B) + out1 (glob bcast)
    float* cellchunk = out + CELL_OUT_OFF + (rowbase + p * 64) * 117;
    #pragma unroll
    for (int i = 0; i < 15; ++i) {
      int idx = i * 512 + tid;
      if (idx < 7488) {
        int n = idx / 117;
        int gg = idx - n * 117;
        cellchunk[idx] = C[n * 128 + gg];
      }
    }
    float4 gv = make_float4(gb, gb, gb, gb);
    float4* o1v = (float4*)(out + OUT1_OUT_OFF + (rowbase + p * 64) * 117);
    #pragma unroll
    for (int i = 0; i < 4; ++i) {
      int idx = i * 512 + tid;
      if (idx < 1872) o1v[idx] = gv;
    }
    // spot partials for this pass
    {
      int grp = tid >> 7, t = tid & 127;
      float s = 0.f;
      #pragma unroll
      for (int n = 0; n < 16; ++n) s += C[(grp * 16 + n) * 128 + t];
      red[grp * 128 + t] = s;
    }
    __syncthreads();
    if (tid < 128)
      part += red[tid] + red[128 + tid] + red[256 + tid] + red[384 + tid];
  }
  if (tid < 128)
    spotp[(size_t)(b * 2 + half) * 128 + tid] = part;
}

// spot[b][g] = sum of 2 half partials
__global__ __launch_bounds__(256) void spot_reduce(
    const float* __restrict__ spotp, float* __restrict__ out) {
  int idx = blockIdx.x * 256 + threadIdx.x;   // exactly 117*256 = 29952
  int b = idx / 117;
  int g = idx - b * 117;
  float s = spotp[(size_t)(b * 2 + 0) * 128 + g] +
            spotp[(size_t)(b * 2 + 1) * 128 + g];
  out[SPOT_OUT_OFF + idx] = s;
}

extern "C" void kernel_launch(void* const* d_in, const int* in_sizes, int n_in,
                              void* d_out, int out_size, void* d_ws, size_t ws_size,
                              hipStream_t stream) {
  const float* images      = (const float*)d_in[0];
  const float* spot_images = (const float*)d_in[1];
  // d_in[2] = gene_expression (unused by the reference)
  const float* W_emph = (const float*)d_in[3];
  const float* b_emph = (const float*)d_in[4];
  const float* W_reg  = (const float*)d_in[5];
  const float* b_reg  = (const float*)d_in[6];
  const float* W_patch = (const float*)d_in[7];
  const float* b_patch = (const float*)d_in[8];
  const float* W_glob  = (const float*)d_in[9];
  const float* b_glob  = (const float*)d_in[10];
  float* out = (float*)d_out;

  unsigned short* wb   = (unsigned short*)((char*)d_ws + WB_OFF);
  unsigned short* wbig = (unsigned short*)((char*)d_ws + WBIG_OFF);
  float* glob  = (float*)((char*)d_ws + GLOB_OFF);
  float* spotp = (float*)((char*)d_ws + SPOT_OFF);

  prep_kernel<<<496, 128, 0, stream>>>(spot_images, W_patch, b_patch, W_glob,
                                       b_glob, W_reg, W_emph, b_emph, wb, wbig,
                                       glob);
  main_kernel<<<512, 512, 0, stream>>>(images, b_reg, wb, wbig, glob, out,
                                       spotp);
  spot_reduce<<<117, 256, 0, stream>>>(spotp, out);
}

// Round 9
// 55.729 us; speedup vs baseline: 1.3408x; 1.1102x over previous
//
#include <hip/hip_runtime.h>

// B=256, N=512 cells, G=117 genes, CH=25 conv channels.
// Conv as MFMA with REGISTER handoff to the regression matmul (r8 structure),
// plus LDS-staged weights: per jt, the 12 KB slab [4KB W_big a-frags | 8KB
// W_reg b-frags] is loaded ONCE per block via global_load_lds (double-
// buffered, one barrier per jt) instead of per-wave from L2 (was 983 MB of
// redundant L2 reads -> now 123 MB).
//   per wave (ct = 32-cell group), per jt (32 j's):
//     o = W_big^T(32j x 64i) @ img(64i x 32cells)      [4 MFMA 32x32x16]
//     relu -> v_cvt_pk_bf16_f32 (8) -> permlane32_swap (4) => af0, af1
//     acc_q += af @ W_reg^T(kstep, gene quad q)        [8 MFMA]
// Block = 256 cells x 128 genes, 512 thr = 8 waves = 8 ct groups.
// Epilogue: 4 passes of C[64][128] f32 LDS -> coalesced cell + out1 streams.

typedef __attribute__((ext_vector_type(16))) float f32x16;
typedef __attribute__((ext_vector_type(8))) short short8;
typedef __attribute__((ext_vector_type(2))) unsigned int uint2v;
typedef __attribute__((ext_vector_type(4))) unsigned int uint4v;

#define WCOMB_OFF 0          // 245760 B : [20 jt][12288 B = 4KB a | 8KB wb]
#define GLOB_OFF  245760     // 1024 B   : glob[256]
#define SPOT_OFF  246784     // 256 KB   : [256][2][128] f32 partials

#define SPOT_OUT_OFF 0
#define CELL_OUT_OFF 29952
#define OUT1_OUT_OFF 15365376

__device__ __forceinline__ unsigned short f2bf(float x) {
  unsigned int u = __builtin_bit_cast(unsigned int, x);
  u = (u + 0x7FFFu + ((u >> 16) & 1u)) >> 16;   // RNE
  return (unsigned short)u;
}

__device__ __forceinline__ unsigned int cvt_pk_bf16(float lo, float hi) {
  unsigned int w;
  asm("v_cvt_pk_bf16_f32 %0, %1, %2" : "=v"(w) : "v"(lo), "v"(hi));
  return w;
}

__device__ __forceinline__ void gload16(const void* g, void* l) {
  __builtin_amdgcn_global_load_lds(
      (const __attribute__((address_space(1))) void*)g,
      (__attribute__((address_space(3))) void*)l, 16, 0, 0);
}

// blocks 0..255: glob ; 256..335: a-frags (jt x s) ; 336..495: wb (sg x q)
__global__ __launch_bounds__(128) void prep_kernel(
    const float* __restrict__ spot_images, const float* __restrict__ W_patch,
    const float* __restrict__ b_patch, const float* __restrict__ W_glob,
    const float* __restrict__ b_glob, const float* __restrict__ W_reg,
    const float* __restrict__ W_emph, const float* __restrict__ b_emph,
    unsigned short* __restrict__ wcomb, float* __restrict__ glob) {
  int bid = blockIdx.x;
  int tid = threadIdx.x;
  if (bid < 256) {
    __shared__ float red[75];
    if (tid < 75) {
      int token = tid / 3;
      int chan = tid - token * 3;
      int ty = token / 5, tx = token - ty * 5;
      const float* img = spot_images + bid * 784 + (ty * 5) * 28 + tx * 5;
      float a = 0.f;
      #pragma unroll
      for (int i = 0; i < 5; ++i)
        #pragma unroll
        for (int j = 0; j < 5; ++j)
          a = fmaf(img[i * 28 + j], W_patch[chan * 25 + i * 5 + j], a);
      a += b_patch[chan];
      red[tid] = a * W_glob[tid];
    }
    __syncthreads();
    if (tid == 0) {
      float s = b_glob[0];
      for (int k = 0; k < 75; ++k) s += red[k];
      glob[bid] = (s > 0.f) ? s : expm1f(s);
    }
  } else if (bid < 336) {
    int idx = bid - 256;               // jt*4 + s
    int jt = idx >> 2, s = idx & 3;
    if (tid < 64) {
      int j = jt * 32 + (tid & 31);
      int h = tid >> 5;
      unsigned short hv[8];
      #pragma unroll
      for (int jj = 0; jj < 8; ++jj) {
        int i = s * 16 + h * 8 + jj;
        float val = 0.f;
        if (j < 625) {
          int ch = j / 25, p = j % 25;
          int oy = p / 5, ox = p - oy * 5;
          if (i < 49) {
            int iy = i / 7, ix = i - iy * 7;
            int ky = iy - oy, kx = ix - ox;
            if (ky >= 0 && ky < 3 && kx >= 0 && kx < 3)
              val = W_emph[ch * 9 + ky * 3 + kx];
          } else if (i == 49) {
            val = b_emph[ch];
          }
        }
        hv[jj] = f2bf(val);
      }
      unsigned int u[4];
      #pragma unroll
      for (int k = 0; k < 4; ++k)
        u[k] = (unsigned int)hv[2 * k] | ((unsigned int)hv[2 * k + 1] << 16);
      // slab layout: [jt][chunk s = 0..3][lane][16B]
      ((uint4*)wcomb)[jt * 768 + s * 64 + tid] = make_uint4(u[0], u[1], u[2], u[3]);
    }
  } else {
    int idx = bid - 336;               // sg*4 + q   (sg = kstep 0..39)
    int sg = idx >> 2, q = idx & 3;
    if (tid < 64) {
      int g = q * 32 + (tid & 31);
      int h = tid >> 5;
      unsigned short hv[8];
      #pragma unroll
      for (int jj = 0; jj < 8; ++jj) {
        int k = sg * 16 + h * 8 + jj;
        float val = (g < 117 && k < 625) ? W_reg[g * 625 + k] : 0.f;
        hv[jj] = f2bf(val);
      }
      unsigned int u[4];
      #pragma unroll
      for (int k = 0; k < 4; ++k)
        u[k] = (unsigned int)hv[2 * k] | ((unsigned int)hv[2 * k + 1] << 16);
      int jt = sg >> 1, c = (sg & 1) * 4 + q;   // chunk 0..7 within wb half
      ((uint4*)wcomb)[jt * 768 + 256 + c * 64 + tid] =
          make_uint4(u[0], u[1], u[2], u[3]);
    }
  }
}

// One block = (batch b, 256-cell half). 512 threads = 8 waves (ct = cell group).
__global__ __launch_bounds__(512, 4) void main_kernel(
    const float* __restrict__ images, const float* __restrict__ b_reg,
    const unsigned short* __restrict__ wcomb, const float* __restrict__ glob,
    float* __restrict__ out, float* __restrict__ spotp) {
  __shared__ char smem[59392];
  unsigned short* imgbs = (unsigned short*)smem;  // 32768 B [8 kc][256 cell][8]
  char* wbuf = smem + 32768;                      // 24576 B = 2 x 12288 dbuf
  float* C = (float*)smem;                        // 32768 B [64][128] (epilogue)
  float* red = (float*)(smem + 57344);            // 2048 B [4][128]
  int tid = threadIdx.x;
  int bid = blockIdx.x;
  int b = bid >> 1, half = bid & 1;
  int n0 = half * 256;

  int l = tid & 63;
  int ct = __builtin_amdgcn_readfirstlane(tid >> 6);   // wave 0..7
  const char* wcombB = (const char*)wcomb;

  // stage weight slab for jt into wbuf[buf]; 12 chunks of 1KB across 8 waves
  auto stage = [&](int jt, int buf) {
    const char* s0 = wcombB + jt * 12288 + ct * 1024 + l * 16;
    char* d0 = wbuf + buf * 12288 + ct * 1024;   // wave-uniform base
    gload16(s0, d0);
    if (ct < 4) gload16(s0 + 8192, d0 + 8192);
  };

  // ---- stage img -> bf16 chunk-major LDS (i=49 -> 1.0 bias column) ----
  #pragma unroll
  for (int it = 0; it < 4; ++it) {
    int u = it * 512 + tid;
    int cell = u & 255, kc = u >> 8;
    const float* src = images + (size_t)(b * 512 + n0 + cell) * 49 + kc * 8;
    float v[8];
    #pragma unroll
    for (int j = 0; j < 8; ++j) v[j] = 0.f;
    if (kc < 6) {
      #pragma unroll
      for (int j = 0; j < 8; ++j) v[j] = src[j];
    } else if (kc == 6) {
      v[0] = src[0];
      v[1] = 1.0f;
    }
    unsigned int uu[4];
    #pragma unroll
    for (int k = 0; k < 4; ++k) uu[k] = cvt_pk_bf16(v[2 * k], v[2 * k + 1]);
    ((uint4*)imgbs)[kc * 256 + cell] = make_uint4(uu[0], uu[1], uu[2], uu[3]);
  }
  stage(0, 0);          // prologue weight stage (drained by the barrier)
  __syncthreads();

  int m = l & 31, hh = l >> 5;
  const short8* imgb8 = (const short8*)imgbs;

  // persistent img B-frags (s = 0..3), 16 VGPR
  short8 bi0 = imgb8[(0 + hh) * 256 + ct * 32 + m];
  short8 bi1 = imgb8[(2 + hh) * 256 + ct * 32 + m];
  short8 bi2 = imgb8[(4 + hh) * 256 + ct * 32 + m];
  short8 bi3 = imgb8[(6 + hh) * 256 + ct * 32 + m];

  f32x16 acc0, acc1, acc2, acc3;
  #pragma unroll
  for (int i = 0; i < 16; ++i) {
    acc0[i] = 0.f; acc1[i] = 0.f; acc2[i] = 0.f; acc3[i] = 0.f;
  }

  for (int jt = 0; jt < 20; ++jt) {
    if (jt < 19) stage(jt + 1, (jt + 1) & 1);   // prefetch next slab

    const short8* wB = (const short8*)(wbuf + (jt & 1) * 12288);
    short8 a0 = wB[l];
    short8 a1 = wB[64 + l];
    short8 a2 = wB[128 + l];
    short8 a3 = wB[192 + l];

    // mm1: conv for 32 cells x 32 j (once)
    f32x16 o;
    #pragma unroll
    for (int i = 0; i < 16; ++i) o[i] = 0.f;
    o = __builtin_amdgcn_mfma_f32_32x32x16_bf16(a0, bi0, o, 0, 0, 0);
    o = __builtin_amdgcn_mfma_f32_32x32x16_bf16(a1, bi1, o, 0, 0, 0);
    o = __builtin_amdgcn_mfma_f32_32x32x16_bf16(a2, bi2, o, 0, 0, 0);
    o = __builtin_amdgcn_mfma_f32_32x32x16_bf16(a3, bi3, o, 0, 0, 0);

    // relu + pack to bf16; hh-half exchange (one swap fills 2 words)
    unsigned int W[8];
    #pragma unroll
    for (int q = 0; q < 8; ++q)
      W[q] = cvt_pk_bf16(fmaxf(o[2 * q], 0.f), fmaxf(o[2 * q + 1], 0.f));
    uint2v s02 = __builtin_amdgcn_permlane32_swap(W[0], W[2], false, false);
    uint2v s13 = __builtin_amdgcn_permlane32_swap(W[1], W[3], false, false);
    uint2v s46 = __builtin_amdgcn_permlane32_swap(W[4], W[6], false, false);
    uint2v s57 = __builtin_amdgcn_permlane32_swap(W[5], W[7], false, false);
    uint4v f0 = {s02[0], s13[0], s02[1], s13[1]};
    uint4v f1 = {s46[0], s57[0], s46[1], s57[1]};
    short8 af0 = __builtin_bit_cast(short8, f0);
    short8 af1 = __builtin_bit_cast(short8, f1);

    // mm2: all 4 gene quads, ksteps 2jt (af0, chunks 0-3) / 2jt+1 (af1, 4-7)
    acc0 = __builtin_amdgcn_mfma_f32_32x32x16_bf16(af0, wB[256 + l], acc0, 0, 0, 0);
    acc1 = __builtin_amdgcn_mfma_f32_32x32x16_bf16(af0, wB[320 + l], acc1, 0, 0, 0);
    acc2 = __builtin_amdgcn_mfma_f32_32x32x16_bf16(af0, wB[384 + l], acc2, 0, 0, 0);
    acc3 = __builtin_amdgcn_mfma_f32_32x32x16_bf16(af0, wB[448 + l], acc3, 0, 0, 0);
    acc0 = __builtin_amdgcn_mfma_f32_32x32x16_bf16(af1, wB[512 + l], acc0, 0, 0, 0);
    acc1 = __builtin_amdgcn_mfma_f32_32x32x16_bf16(af1, wB[576 + l], acc1, 0, 0, 0);
    acc2 = __builtin_amdgcn_mfma_f32_32x32x16_bf16(af1, wB[640 + l], acc2, 0, 0, 0);
    acc3 = __builtin_amdgcn_mfma_f32_32x32x16_bf16(af1, wB[704 + l], acc3, 0, 0, 0);

    __syncthreads();   // reads of wbuf[jt&1] done; stage(jt+1) landed
  }

  // ---- epilogue: 4 passes of 64 cells through C[64][128] ----
  float gb = glob[b];
  float part = 0.f;
  size_t rowbase = (size_t)(b * 512 + n0);
  #pragma unroll
  for (int p = 0; p < 4; ++p) {
    if ((ct >> 1) == p) {
      int nb = (ct & 1) * 32;
      #define EPI(Q, ACC)                                                  \
        {                                                                  \
          int g = (Q)*32 + m;                                              \
          float br = (g < 117) ? b_reg[g] : 0.f;                           \
          _Pragma("unroll")                                                \
          for (int reg = 0; reg < 16; ++reg) {                             \
            int n = nb + (reg & 3) + 8 * (reg >> 2) + 4 * hh;              \
            C[n * 128 + g] = fmaxf(ACC[reg] + br + gb, 0.f);               \
          }                                                                \
        }
      EPI(0, acc0) EPI(1, acc1) EPI(2, acc2) EPI(3, acc3)
      #undef EPI
    }
    __syncthreads();
    // coalesced streams: cell chunk (29952 B) + out1 (glob bcast)
    float* cellchunk = out + CELL_OUT_OFF + (rowbase + p * 64) * 117;
    #pragma unroll
    for (int i = 0; i < 15; ++i) {
      int idx = i * 512 + tid;
      if (idx < 7488) {
        int n = idx / 117;
        int gg = idx - n * 117;
        cellchunk[idx] = C[n * 128 + gg];
      }
    }
    float4 gv = make_float4(gb, gb, gb, gb);
    float4* o1v = (float4*)(out + OUT1_OUT_OFF + (rowbase + p * 64) * 117);
    #pragma unroll
    for (int i = 0; i < 4; ++i) {
      int idx = i * 512 + tid;
      if (idx < 1872) o1v[idx] = gv;
    }
    // spot partials for this pass
    {
      int grp = tid >> 7, t = tid & 127;
      float s = 0.f;
      #pragma unroll
      for (int n = 0; n < 16; ++n) s += C[(grp * 16 + n) * 128 + t];
      red[grp * 128 + t] = s;
    }
    __syncthreads();
    if (tid < 128)
      part += red[tid] + red[128 + tid] + red[256 + tid] + red[384 + tid];
  }
  if (tid < 128)
    spotp[(size_t)(b * 2 + half) * 128 + tid] = part;
}

// spot[b][g] = sum of 2 half partials
__global__ __launch_bounds__(256) void spot_reduce(
    const float* __restrict__ spotp, float* __restrict__ out) {
  int idx = blockIdx.x * 256 + threadIdx.x;   // exactly 117*256 = 29952
  int b = idx / 117;
  int g = idx - b * 117;
  float s = spotp[(size_t)(b * 2 + 0) * 128 + g] +
            spotp[(size_t)(b * 2 + 1) * 128 + g];
  out[SPOT_OUT_OFF + idx] = s;
}

extern "C" void kernel_launch(void* const* d_in, const int* in_sizes, int n_in,
                              void* d_out, int out_size, void* d_ws, size_t ws_size,
                              hipStream_t stream) {
  const float* images      = (const float*)d_in[0];
  const float* spot_images = (const float*)d_in[1];
  // d_in[2] = gene_expression (unused by the reference)
  const float* W_emph = (const float*)d_in[3];
  const float* b_emph = (const float*)d_in[4];
  const float* W_reg  = (const float*)d_in[5];
  const float* b_reg  = (const float*)d_in[6];
  const float* W_patch = (const float*)d_in[7];
  const float* b_patch = (const float*)d_in[8];
  const float* W_glob  = (const float*)d_in[9];
  const float* b_glob  = (const float*)d_in[10];
  float* out = (float*)d_out;

  unsigned short* wcomb = (unsigned short*)((char*)d_ws + WCOMB_OFF);
  float* glob  = (float*)((char*)d_ws + GLOB_OFF);
  float* spotp = (float*)((char*)d_ws + SPOT_OFF);

  prep_kernel<<<496, 128, 0, stream>>>(spot_images, W_patch, b_patch, W_glob,
                                       b_glob, W_reg, W_emph, b_emph, wcomb,
                                       glob);
  main_kernel<<<512, 512, 0, stream>>>(images, b_reg, wcomb, glob, out, spotp);
  spot_reduce<<<117, 256, 0, stream>>>(spotp, out);
}

// Round 10
// 52.315 us; speedup vs baseline: 1.4283x; 1.0653x over previous
//
#include <hip/hip_runtime.h>

// B=256, N=512 cells, G=117 genes, CH=25 conv channels.
// r9 compute structure (conv-as-MFMA, register handoff via cvt_pk+permlane,
// LDS-staged 12KB weight slabs, double-buffered, 1 barrier/jt) with the
// WRITE STREAM rescheduled:
//  - out1 (glob broadcast, 61 MB) is issued DURING the jt loop (1 float4 per
//    thread on 15 of 20 iterations) - the per-jt barrier drains ~12KB/CU,
//    absorbed by HBM concurrently with the LDS-bound compute.
//  - cell stores are issued after the red barrier of each epilogue pass, so
//    only the NEXT pass's WAR barrier sees them (paced drain); the last
//    pass's stores drain at dispatch end, barrier-free.

typedef __attribute__((ext_vector_type(16))) float f32x16;
typedef __attribute__((ext_vector_type(8))) short short8;
typedef __attribute__((ext_vector_type(2))) unsigned int uint2v;
typedef __attribute__((ext_vector_type(4))) unsigned int uint4v;

#define WCOMB_OFF 0          // 245760 B : [20 jt][12288 B = 4KB a | 8KB wb]
#define GLOB_OFF  245760     // 1024 B   : glob[256]
#define SPOT_OFF  246784     // 256 KB   : [256][2][128] f32 partials

#define SPOT_OUT_OFF 0
#define CELL_OUT_OFF 29952
#define OUT1_OUT_OFF 15365376

__device__ __forceinline__ unsigned short f2bf(float x) {
  unsigned int u = __builtin_bit_cast(unsigned int, x);
  u = (u + 0x7FFFu + ((u >> 16) & 1u)) >> 16;   // RNE
  return (unsigned short)u;
}

__device__ __forceinline__ unsigned int cvt_pk_bf16(float lo, float hi) {
  unsigned int w;
  asm("v_cvt_pk_bf16_f32 %0, %1, %2" : "=v"(w) : "v"(lo), "v"(hi));
  return w;
}

__device__ __forceinline__ void gload16(const void* g, void* l) {
  __builtin_amdgcn_global_load_lds(
      (const __attribute__((address_space(1))) void*)g,
      (__attribute__((address_space(3))) void*)l, 16, 0, 0);
}

// blocks 0..255: glob ; 256..335: a-frags (jt x s) ; 336..495: wb (sg x q)
__global__ __launch_bounds__(128) void prep_kernel(
    const float* __restrict__ spot_images, const float* __restrict__ W_patch,
    const float* __restrict__ b_patch, const float* __restrict__ W_glob,
    const float* __restrict__ b_glob, const float* __restrict__ W_reg,
    const float* __restrict__ W_emph, const float* __restrict__ b_emph,
    unsigned short* __restrict__ wcomb, float* __restrict__ glob) {
  int bid = blockIdx.x;
  int tid = threadIdx.x;
  if (bid < 256) {
    __shared__ float red[75];
    if (tid < 75) {
      int token = tid / 3;
      int chan = tid - token * 3;
      int ty = token / 5, tx = token - ty * 5;
      const float* img = spot_images + bid * 784 + (ty * 5) * 28 + tx * 5;
      float a = 0.f;
      #pragma unroll
      for (int i = 0; i < 5; ++i)
        #pragma unroll
        for (int j = 0; j < 5; ++j)
          a = fmaf(img[i * 28 + j], W_patch[chan * 25 + i * 5 + j], a);
      a += b_patch[chan];
      red[tid] = a * W_glob[tid];
    }
    __syncthreads();
    if (tid == 0) {
      float s = b_glob[0];
      for (int k = 0; k < 75; ++k) s += red[k];
      glob[bid] = (s > 0.f) ? s : expm1f(s);
    }
  } else if (bid < 336) {
    int idx = bid - 256;               // jt*4 + s
    int jt = idx >> 2, s = idx & 3;
    if (tid < 64) {
      int j = jt * 32 + (tid & 31);
      int h = tid >> 5;
      unsigned short hv[8];
      #pragma unroll
      for (int jj = 0; jj < 8; ++jj) {
        int i = s * 16 + h * 8 + jj;
        float val = 0.f;
        if (j < 625) {
          int ch = j / 25, p = j % 25;
          int oy = p / 5, ox = p - oy * 5;
          if (i < 49) {
            int iy = i / 7, ix = i - iy * 7;
            int ky = iy - oy, kx = ix - ox;
            if (ky >= 0 && ky < 3 && kx >= 0 && kx < 3)
              val = W_emph[ch * 9 + ky * 3 + kx];
          } else if (i == 49) {
            val = b_emph[ch];
          }
        }
        hv[jj] = f2bf(val);
      }
      unsigned int u[4];
      #pragma unroll
      for (int k = 0; k < 4; ++k)
        u[k] = (unsigned int)hv[2 * k] | ((unsigned int)hv[2 * k + 1] << 16);
      ((uint4*)wcomb)[jt * 768 + s * 64 + tid] = make_uint4(u[0], u[1], u[2], u[3]);
    }
  } else {
    int idx = bid - 336;               // sg*4 + q   (sg = kstep 0..39)
    int sg = idx >> 2, q = idx & 3;
    if (tid < 64) {
      int g = q * 32 + (tid & 31);
      int h = tid >> 5;
      unsigned short hv[8];
      #pragma unroll
      for (int jj = 0; jj < 8; ++jj) {
        int k = sg * 16 + h * 8 + jj;
        float val = (g < 117 && k < 625) ? W_reg[g * 625 + k] : 0.f;
        hv[jj] = f2bf(val);
      }
      unsigned int u[4];
      #pragma unroll
      for (int k = 0; k < 4; ++k)
        u[k] = (unsigned int)hv[2 * k] | ((unsigned int)hv[2 * k + 1] << 16);
      int jt = sg >> 1, c = (sg & 1) * 4 + q;   // chunk 0..7 within wb half
      ((uint4*)wcomb)[jt * 768 + 256 + c * 64 + tid] =
          make_uint4(u[0], u[1], u[2], u[3]);
    }
  }
}

// One block = (batch b, 256-cell half). 512 threads = 8 waves (ct = cell group).
__global__ __launch_bounds__(512) void main_kernel(
    const float* __restrict__ images, const float* __restrict__ b_reg,
    const unsigned short* __restrict__ wcomb, const float* __restrict__ glob,
    float* __restrict__ out, float* __restrict__ spotp) {
  __shared__ char smem[59392];
  unsigned short* imgbs = (unsigned short*)smem;  // 32768 B [8 kc][256 cell][8]
  char* wbuf = smem + 32768;                      // 24576 B = 2 x 12288 dbuf
  float* C = (float*)smem;                        // 32768 B [64][128] (epilogue)
  float* red = (float*)(smem + 57344);            // 2048 B [4][128]
  int tid = threadIdx.x;
  int bid = blockIdx.x;
  int b = bid >> 1, half = bid & 1;
  int n0 = half * 256;

  int l = tid & 63;
  int ct = __builtin_amdgcn_readfirstlane(tid >> 6);   // wave 0..7
  const char* wcombB = (const char*)wcomb;

  float gb = glob[b];
  size_t rowbase = (size_t)(b * 512 + n0);
  float4 gv = make_float4(gb, gb, gb, gb);
  float4* o1v = (float4*)(out + OUT1_OUT_OFF + rowbase * 117);  // 7488 float4

  // stage weight slab for jt into wbuf[buf]; 12 chunks of 1KB across 8 waves
  auto stage = [&](int jt, int buf) {
    const char* s0 = wcombB + jt * 12288 + ct * 1024 + l * 16;
    char* d0 = wbuf + buf * 12288 + ct * 1024;   // wave-uniform base
    gload16(s0, d0);
    if (ct < 4) gload16(s0 + 8192, d0 + 8192);
  };

  // ---- stage img -> bf16 chunk-major LDS (i=49 -> 1.0 bias column) ----
  #pragma unroll
  for (int it = 0; it < 4; ++it) {
    int u = it * 512 + tid;
    int cell = u & 255, kc = u >> 8;
    const float* src = images + (size_t)(b * 512 + n0 + cell) * 49 + kc * 8;
    float v[8];
    #pragma unroll
    for (int j = 0; j < 8; ++j) v[j] = 0.f;
    if (kc < 6) {
      #pragma unroll
      for (int j = 0; j < 8; ++j) v[j] = src[j];
    } else if (kc == 6) {
      v[0] = src[0];
      v[1] = 1.0f;
    }
    unsigned int uu[4];
    #pragma unroll
    for (int k = 0; k < 4; ++k) uu[k] = cvt_pk_bf16(v[2 * k], v[2 * k + 1]);
    ((uint4*)imgbs)[kc * 256 + cell] = make_uint4(uu[0], uu[1], uu[2], uu[3]);
  }
  stage(0, 0);          // prologue weight stage (drained by the barrier)
  __syncthreads();

  int m = l & 31, hh = l >> 5;
  const short8* imgb8 = (const short8*)imgbs;

  // persistent img B-frags (s = 0..3), 16 VGPR
  short8 bi0 = imgb8[(0 + hh) * 256 + ct * 32 + m];
  short8 bi1 = imgb8[(2 + hh) * 256 + ct * 32 + m];
  short8 bi2 = imgb8[(4 + hh) * 256 + ct * 32 + m];
  short8 bi3 = imgb8[(6 + hh) * 256 + ct * 32 + m];

  f32x16 acc0, acc1, acc2, acc3;
  #pragma unroll
  for (int i = 0; i < 16; ++i) {
    acc0[i] = 0.f; acc1[i] = 0.f; acc2[i] = 0.f; acc3[i] = 0.f;
  }

  for (int jt = 0; jt < 20; ++jt) {
    if (jt < 19) stage(jt + 1, (jt + 1) & 1);   // prefetch next slab

    // spread out1 stream across the loop (61 MB leaves during compute)
    if (jt < 15) {
      int idx = jt * 512 + tid;
      if (idx < 7488) o1v[idx] = gv;
    }

    const short8* wB = (const short8*)(wbuf + (jt & 1) * 12288);
    short8 a0 = wB[l];
    short8 a1 = wB[64 + l];
    short8 a2 = wB[128 + l];
    short8 a3 = wB[192 + l];

    // mm1: conv for 32 cells x 32 j (once)
    f32x16 o;
    #pragma unroll
    for (int i = 0; i < 16; ++i) o[i] = 0.f;
    o = __builtin_amdgcn_mfma_f32_32x32x16_bf16(a0, bi0, o, 0, 0, 0);
    o = __builtin_amdgcn_mfma_f32_32x32x16_bf16(a1, bi1, o, 0, 0, 0);
    o = __builtin_amdgcn_mfma_f32_32x32x16_bf16(a2, bi2, o, 0, 0, 0);
    o = __builtin_amdgcn_mfma_f32_32x32x16_bf16(a3, bi3, o, 0, 0, 0);

    // relu + pack to bf16; hh-half exchange (one swap fills 2 words)
    unsigned int W[8];
    #pragma unroll
    for (int q = 0; q < 8; ++q)
      W[q] = cvt_pk_bf16(fmaxf(o[2 * q], 0.f), fmaxf(o[2 * q + 1], 0.f));
    uint2v s02 = __builtin_amdgcn_permlane32_swap(W[0], W[2], false, false);
    uint2v s13 = __builtin_amdgcn_permlane32_swap(W[1], W[3], false, false);
    uint2v s46 = __builtin_amdgcn_permlane32_swap(W[4], W[6], false, false);
    uint2v s57 = __builtin_amdgcn_permlane32_swap(W[5], W[7], false, false);
    uint4v f0 = {s02[0], s13[0], s02[1], s13[1]};
    uint4v f1 = {s46[0], s57[0], s46[1], s57[1]};
    short8 af0 = __builtin_bit_cast(short8, f0);
    short8 af1 = __builtin_bit_cast(short8, f1);

    // mm2: all 4 gene quads, ksteps 2jt (af0, chunks 0-3) / 2jt+1 (af1, 4-7)
    acc0 = __builtin_amdgcn_mfma_f32_32x32x16_bf16(af0, wB[256 + l], acc0, 0, 0, 0);
    acc1 = __builtin_amdgcn_mfma_f32_32x32x16_bf16(af0, wB[320 + l], acc1, 0, 0, 0);
    acc2 = __builtin_amdgcn_mfma_f32_32x32x16_bf16(af0, wB[384 + l], acc2, 0, 0, 0);
    acc3 = __builtin_amdgcn_mfma_f32_32x32x16_bf16(af0, wB[448 + l], acc3, 0, 0, 0);
    acc0 = __builtin_amdgcn_mfma_f32_32x32x16_bf16(af1, wB[512 + l], acc0, 0, 0, 0);
    acc1 = __builtin_amdgcn_mfma_f32_32x32x16_bf16(af1, wB[576 + l], acc1, 0, 0, 0);
    acc2 = __builtin_amdgcn_mfma_f32_32x32x16_bf16(af1, wB[640 + l], acc2, 0, 0, 0);
    acc3 = __builtin_amdgcn_mfma_f32_32x32x16_bf16(af1, wB[704 + l], acc3, 0, 0, 0);

    __syncthreads();   // reads of wbuf[jt&1] done; stage(jt+1) landed
  }

  // ---- epilogue: 4 passes of 64 cells through C[64][128] ----
  // stores for pass p are issued AFTER the red barrier, so only the next
  // pass's WAR barrier drains them (paced); last pass drains at dispatch end.
  float part = 0.f;
  #pragma unroll
  for (int p = 0; p < 4; ++p) {
    if ((ct >> 1) == p) {
      int nb = (ct & 1) * 32;
      #define EPI(Q, ACC)                                                  \
        {                                                                  \
          int g = (Q)*32 + m;                                              \
          float br = (g < 117) ? b_reg[g] : 0.f;                           \
          _Pragma("unroll")                                                \
          for (int reg = 0; reg < 16; ++reg) {                             \
            int n = nb + (reg & 3) + 8 * (reg >> 2) + 4 * hh;              \
            C[n * 128 + g] = fmaxf(ACC[reg] + br + gb, 0.f);               \
          }                                                                \
        }
      EPI(0, acc0) EPI(1, acc1) EPI(2, acc2) EPI(3, acc3)
      #undef EPI
    }
    __syncthreads();
    // read C into registers (coalesced layout decode)
    float cellreg[15];
    #pragma unroll
    for (int i = 0; i < 15; ++i) {
      int idx = i * 512 + tid;
      int n = idx / 117;
      int gg = idx - n * 117;
      cellreg[i] = (idx < 7488) ? C[n * 128 + gg] : 0.f;
    }
    // spot partials
    {
      int grp = tid >> 7, t = tid & 127;
      float s = 0.f;
      #pragma unroll
      for (int n = 0; n < 16; ++n) s += C[(grp * 16 + n) * 128 + t];
      red[grp * 128 + t] = s;
    }
    __syncthreads();
    if (tid < 128)
      part += red[tid] + red[128 + tid] + red[256 + tid] + red[384 + tid];
    // issue this pass's cell stores (no barrier between here and next WAR bar)
    float* cellchunk = out + CELL_OUT_OFF + (rowbase + p * 64) * 117;
    #pragma unroll
    for (int i = 0; i < 15; ++i) {
      int idx = i * 512 + tid;
      if (idx < 7488) cellchunk[idx] = cellreg[i];
    }
  }
  if (tid < 128)
    spotp[(size_t)(b * 2 + half) * 128 + tid] = part;
}

// spot[b][g] = sum of 2 half partials
__global__ __launch_bounds__(256) void spot_reduce(
    const float* __restrict__ spotp, float* __restrict__ out) {
  int idx = blockIdx.x * 256 + threadIdx.x;   // exactly 117*256 = 29952
  int b = idx / 117;
  int g = idx - b * 117;
  float s = spotp[(size_t)(b * 2 + 0) * 128 + g] +
            spotp[(size_t)(b * 2 + 1) * 128 + g];
  out[SPOT_OUT_OFF + idx] = s;
}

extern "C" void kernel_launch(void* const* d_in, const int* in_sizes, int n_in,
                              void* d_out, int out_size, void* d_ws, size_t ws_size,
                              hipStream_t stream) {
  const float* images      = (const float*)d_in[0];
  const float* spot_images = (const float*)d_in[1];
  // d_in[2] = gene_expression (unused by the reference)
  const float* W_emph = (const float*)d_in[3];
  const float* b_emph = (const float*)d_in[4];
  const float* W_reg  = (const float*)d_in[5];
  const float* b_reg  = (const float*)d_in[6];
  const float* W_patch = (const float*)d_in[7];
  const float* b_patch = (const float*)d_in[8];
  const float* W_glob  = (const float*)d_in[9];
  const float* b_glob  = (const float*)d_in[10];
  float* out = (float*)d_out;

  unsigned short* wcomb = (unsigned short*)((char*)d_ws + WCOMB_OFF);
  float* glob  = (float*)((char*)d_ws + GLOB_OFF);
  float* spotp = (float*)((char*)d_ws + SPOT_OFF);

  prep_kernel<<<496, 128, 0, stream>>>(spot_images, W_patch, b_patch, W_glob,
                                       b_glob, W_reg, W_emph, b_emph, wcomb,
                                       glob);
  main_kernel<<<512, 512, 0, stream>>>(images, b_reg, wcomb, glob, out, spotp);
  spot_reduce<<<117, 256, 0, stream>>>(spotp, out);
}

// Round 11
// 51.270 us; speedup vs baseline: 1.4574x; 1.0204x over previous
//
#include <hip/hip_runtime.h>

// B=256, N=512 cells, G=117 genes, CH=25 conv channels.
// One block = one batch (512 cells), grid 256 = 1 block/CU. 8 waves; each
// wave owns 64 cells (subtiles U/V of 32) x all 128 genes.
// Per jt (32 j's): a-frags read once -> conv U and conv V (8 MFMA);
// relu+cvt_pk+permlane32_swap -> afU0/1, afV0/1; mm2: each wb chunk read
// ONCE and used for BOTH U and V (16 MFMA). LDS traffic per CU per jt = 96KB
// (half of r10). Weight slabs (12KB/jt) staged via global_load_lds, dbuf,
// 1 barrier/jt. out1 streamed during the loop; cell stores paced across the
// 8-pass epilogue; spot computed fully in-block (no reduce kernel).

typedef __attribute__((ext_vector_type(16))) float f32x16;
typedef __attribute__((ext_vector_type(8))) short short8;
typedef __attribute__((ext_vector_type(2))) unsigned int uint2v;
typedef __attribute__((ext_vector_type(4))) unsigned int uint4v;

#define WCOMB_OFF 0          // 245760 B : [20 jt][12288 B = 4KB a | 8KB wb]
#define GLOB_OFF  245760     // 1024 B   : glob[256]

#define SPOT_OUT_OFF 0
#define CELL_OUT_OFF 29952
#define OUT1_OUT_OFF 15365376

__device__ __forceinline__ unsigned short f2bf(float x) {
  unsigned int u = __builtin_bit_cast(unsigned int, x);
  u = (u + 0x7FFFu + ((u >> 16) & 1u)) >> 16;   // RNE
  return (unsigned short)u;
}

__device__ __forceinline__ unsigned int cvt_pk_bf16(float lo, float hi) {
  unsigned int w;
  asm("v_cvt_pk_bf16_f32 %0, %1, %2" : "=v"(w) : "v"(lo), "v"(hi));
  return w;
}

__device__ __forceinline__ void gload16(const void* g, void* l) {
  __builtin_amdgcn_global_load_lds(
      (const __attribute__((address_space(1))) void*)g,
      (__attribute__((address_space(3))) void*)l, 16, 0, 0);
}

// blocks 0..255: glob ; 256..335: a-frags (jt x s) ; 336..495: wb (sg x q)
__global__ __launch_bounds__(128) void prep_kernel(
    const float* __restrict__ spot_images, const float* __restrict__ W_patch,
    const float* __restrict__ b_patch, const float* __restrict__ W_glob,
    const float* __restrict__ b_glob, const float* __restrict__ W_reg,
    const float* __restrict__ W_emph, const float* __restrict__ b_emph,
    unsigned short* __restrict__ wcomb, float* __restrict__ glob) {
  int bid = blockIdx.x;
  int tid = threadIdx.x;
  if (bid < 256) {
    __shared__ float red[75];
    if (tid < 75) {
      int token = tid / 3;
      int chan = tid - token * 3;
      int ty = token / 5, tx = token - ty * 5;
      const float* img = spot_images + bid * 784 + (ty * 5) * 28 + tx * 5;
      float a = 0.f;
      #pragma unroll
      for (int i = 0; i < 5; ++i)
        #pragma unroll
        for (int j = 0; j < 5; ++j)
          a = fmaf(img[i * 28 + j], W_patch[chan * 25 + i * 5 + j], a);
      a += b_patch[chan];
      red[tid] = a * W_glob[tid];
    }
    __syncthreads();
    if (tid == 0) {
      float s = b_glob[0];
      for (int k = 0; k < 75; ++k) s += red[k];
      glob[bid] = (s > 0.f) ? s : expm1f(s);
    }
  } else if (bid < 336) {
    int idx = bid - 256;               // jt*4 + s
    int jt = idx >> 2, s = idx & 3;
    if (tid < 64) {
      int j = jt * 32 + (tid & 31);
      int h = tid >> 5;
      unsigned short hv[8];
      #pragma unroll
      for (int jj = 0; jj < 8; ++jj) {
        int i = s * 16 + h * 8 + jj;
        float val = 0.f;
        if (j < 625) {
          int ch = j / 25, p = j % 25;
          int oy = p / 5, ox = p - oy * 5;
          if (i < 49) {
            int iy = i / 7, ix = i - iy * 7;
            int ky = iy - oy, kx = ix - ox;
            if (ky >= 0 && ky < 3 && kx >= 0 && kx < 3)
              val = W_emph[ch * 9 + ky * 3 + kx];
          } else if (i == 49) {
            val = b_emph[ch];
          }
        }
        hv[jj] = f2bf(val);
      }
      unsigned int u[4];
      #pragma unroll
      for (int k = 0; k < 4; ++k)
        u[k] = (unsigned int)hv[2 * k] | ((unsigned int)hv[2 * k + 1] << 16);
      ((uint4*)wcomb)[jt * 768 + s * 64 + tid] = make_uint4(u[0], u[1], u[2], u[3]);
    }
  } else {
    int idx = bid - 336;               // sg*4 + q   (sg = kstep 0..39)
    int sg = idx >> 2, q = idx & 3;
    if (tid < 64) {
      int g = q * 32 + (tid & 31);
      int h = tid >> 5;
      unsigned short hv[8];
      #pragma unroll
      for (int jj = 0; jj < 8; ++jj) {
        int k = sg * 16 + h * 8 + jj;
        float val = (g < 117 && k < 625) ? W_reg[g * 625 + k] : 0.f;
        hv[jj] = f2bf(val);
      }
      unsigned int u[4];
      #pragma unroll
      for (int k = 0; k < 4; ++k)
        u[k] = (unsigned int)hv[2 * k] | ((unsigned int)hv[2 * k + 1] << 16);
      int jt = sg >> 1, c = (sg & 1) * 4 + q;   // chunk c = ks*4 + q
      ((uint4*)wcomb)[jt * 768 + 256 + c * 64 + tid] =
          make_uint4(u[0], u[1], u[2], u[3]);
    }
  }
}

// One block = batch b (512 cells). 512 threads = 8 waves (ct = 64-cell group).
__global__ __launch_bounds__(512, 2) void main_kernel(
    const float* __restrict__ images, const float* __restrict__ b_reg,
    const unsigned short* __restrict__ wcomb, const float* __restrict__ glob,
    float* __restrict__ out) {
  __shared__ char smem[59392];
  unsigned short* imgbs = (unsigned short*)smem;  // 32768 B [8 kc][256 cell][8]
  char* wbuf = smem + 32768;                      // 24576 B = 2 x 12288 dbuf
  float* C = (float*)smem;                        // 32768 B [64][128] (epilogue)
  float* red = (float*)(smem + 57344);            // 2048 B [4][128]
  int tid = threadIdx.x;
  int b = blockIdx.x;
  int l = tid & 63;
  int ct = __builtin_amdgcn_readfirstlane(tid >> 6);   // wave 0..7
  int m = l & 31, hh = l >> 5;
  const char* wcombB = (const char*)wcomb;
  const short8* imgb8 = (const short8*)imgbs;

  float gb = glob[b];
  size_t rowbase = (size_t)b * 512;
  float4 gv = make_float4(gb, gb, gb, gb);
  float4* o1v = (float4*)(out + OUT1_OUT_OFF + rowbase * 117);  // 14976 float4

  auto stage = [&](int jt, int buf) {
    const char* s0 = wcombB + jt * 12288 + ct * 1024 + l * 16;
    char* d0 = wbuf + buf * 12288 + ct * 1024;   // wave-uniform base
    gload16(s0, d0);
    if (ct < 4) gload16(s0 + 8192, d0 + 8192);
  };

  // stage 256 cells (one half) of img -> bf16 chunk-major LDS
  auto stageimg = [&](int hf) {
    #pragma unroll
    for (int it = 0; it < 4; ++it) {
      int u = it * 512 + tid;
      int cell = u & 255, kc = u >> 8;
      const float* src =
          images + (size_t)(b * 512 + hf * 256 + cell) * 49 + kc * 8;
      float v[8];
      #pragma unroll
      for (int j = 0; j < 8; ++j) v[j] = 0.f;
      if (kc < 6) {
        #pragma unroll
        for (int j = 0; j < 8; ++j) v[j] = src[j];
      } else if (kc == 6) {
        v[0] = src[0];
        v[1] = 1.0f;
      }
      unsigned int uu[4];
      #pragma unroll
      for (int k = 0; k < 4; ++k) uu[k] = cvt_pk_bf16(v[2 * k], v[2 * k + 1]);
      ((uint4*)imgbs)[kc * 256 + cell] = make_uint4(uu[0], uu[1], uu[2], uu[3]);
    }
  };

  // persistent img B-frags: subtile U = cells ct*64+0..31, V = +32..63
  short8 bU0, bU1, bU2, bU3, bV0, bV1, bV2, bV3;
  int base = (ct & 3) * 64;   // local cell base within the half
  stageimg(0);
  __syncthreads();
  if (ct < 4) {
    bU0 = imgb8[(0 + hh) * 256 + base + m];
    bU1 = imgb8[(2 + hh) * 256 + base + m];
    bU2 = imgb8[(4 + hh) * 256 + base + m];
    bU3 = imgb8[(6 + hh) * 256 + base + m];
    bV0 = imgb8[(0 + hh) * 256 + base + 32 + m];
    bV1 = imgb8[(2 + hh) * 256 + base + 32 + m];
    bV2 = imgb8[(4 + hh) * 256 + base + 32 + m];
    bV3 = imgb8[(6 + hh) * 256 + base + 32 + m];
  }
  __syncthreads();
  stageimg(1);
  __syncthreads();
  if (ct >= 4) {
    bU0 = imgb8[(0 + hh) * 256 + base + m];
    bU1 = imgb8[(2 + hh) * 256 + base + m];
    bU2 = imgb8[(4 + hh) * 256 + base + m];
    bU3 = imgb8[(6 + hh) * 256 + base + m];
    bV0 = imgb8[(0 + hh) * 256 + base + 32 + m];
    bV1 = imgb8[(2 + hh) * 256 + base + 32 + m];
    bV2 = imgb8[(4 + hh) * 256 + base + 32 + m];
    bV3 = imgb8[(6 + hh) * 256 + base + 32 + m];
  }
  stage(0, 0);
  __syncthreads();

  f32x16 aU0, aU1, aU2, aU3, aV0, aV1, aV2, aV3;
  #pragma unroll
  for (int i = 0; i < 16; ++i) {
    aU0[i] = 0.f; aU1[i] = 0.f; aU2[i] = 0.f; aU3[i] = 0.f;
    aV0[i] = 0.f; aV1[i] = 0.f; aV2[i] = 0.f; aV3[i] = 0.f;
  }

  for (int jt = 0; jt < 20; ++jt) {
    if (jt < 19) stage(jt + 1, (jt + 1) & 1);   // prefetch next slab
    if (jt < 15) {                              // out1 stream during compute
      int i0 = jt * 1024 + tid;
      o1v[i0] = gv;
      int i1 = i0 + 512;
      if (i1 < 14976) o1v[i1] = gv;
    }

    const short8* wB = (const short8*)(wbuf + (jt & 1) * 12288);
    short8 a0 = wB[l];
    short8 a1 = wB[64 + l];
    short8 a2 = wB[128 + l];
    short8 a3 = wB[192 + l];

    // conv U then pack
    f32x16 o;
    #pragma unroll
    for (int i = 0; i < 16; ++i) o[i] = 0.f;
    o = __builtin_amdgcn_mfma_f32_32x32x16_bf16(a0, bU0, o, 0, 0, 0);
    o = __builtin_amdgcn_mfma_f32_32x32x16_bf16(a1, bU1, o, 0, 0, 0);
    o = __builtin_amdgcn_mfma_f32_32x32x16_bf16(a2, bU2, o, 0, 0, 0);
    o = __builtin_amdgcn_mfma_f32_32x32x16_bf16(a3, bU3, o, 0, 0, 0);
    unsigned int W[8];
    #pragma unroll
    for (int q = 0; q < 8; ++q)
      W[q] = cvt_pk_bf16(fmaxf(o[2 * q], 0.f), fmaxf(o[2 * q + 1], 0.f));
    uint2v s02 = __builtin_amdgcn_permlane32_swap(W[0], W[2], false, false);
    uint2v s13 = __builtin_amdgcn_permlane32_swap(W[1], W[3], false, false);
    uint2v s46 = __builtin_amdgcn_permlane32_swap(W[4], W[6], false, false);
    uint2v s57 = __builtin_amdgcn_permlane32_swap(W[5], W[7], false, false);
    uint4v f0 = {s02[0], s13[0], s02[1], s13[1]};
    uint4v f1 = {s46[0], s57[0], s46[1], s57[1]};
    short8 afU0 = __builtin_bit_cast(short8, f0);
    short8 afU1 = __builtin_bit_cast(short8, f1);

    // conv V then pack (reuses a0-3 and o)
    #pragma unroll
    for (int i = 0; i < 16; ++i) o[i] = 0.f;
    o = __builtin_amdgcn_mfma_f32_32x32x16_bf16(a0, bV0, o, 0, 0, 0);
    o = __builtin_amdgcn_mfma_f32_32x32x16_bf16(a1, bV1, o, 0, 0, 0);
    o = __builtin_amdgcn_mfma_f32_32x32x16_bf16(a2, bV2, o, 0, 0, 0);
    o = __builtin_amdgcn_mfma_f32_32x32x16_bf16(a3, bV3, o, 0, 0, 0);
    #pragma unroll
    for (int q = 0; q < 8; ++q)
      W[q] = cvt_pk_bf16(fmaxf(o[2 * q], 0.f), fmaxf(o[2 * q + 1], 0.f));
    s02 = __builtin_amdgcn_permlane32_swap(W[0], W[2], false, false);
    s13 = __builtin_amdgcn_permlane32_swap(W[1], W[3], false, false);
    s46 = __builtin_amdgcn_permlane32_swap(W[4], W[6], false, false);
    s57 = __builtin_amdgcn_permlane32_swap(W[5], W[7], false, false);
    uint4v g0 = {s02[0], s13[0], s02[1], s13[1]};
    uint4v g1 = {s46[0], s57[0], s46[1], s57[1]};
    short8 afV0 = __builtin_bit_cast(short8, g0);
    short8 afV1 = __builtin_bit_cast(short8, g1);

    // mm2: each wb chunk read once, used for both U and V
    #define MM2(c, AFU, AFV, AU, AV)                                        \
      {                                                                     \
        short8 w = wB[256 + (c)*64 + l];                                    \
        AU = __builtin_amdgcn_mfma_f32_32x32x16_bf16(AFU, w, AU, 0, 0, 0);  \
        AV = __builtin_amdgcn_mfma_f32_32x32x16_bf16(AFV, w, AV, 0, 0, 0);  \
      }
    MM2(0, afU0, afV0, aU0, aV0)
    MM2(1, afU0, afV0, aU1, aV1)
    MM2(2, afU0, afV0, aU2, aV2)
    MM2(3, afU0, afV0, aU3, aV3)
    MM2(4, afU1, afV1, aU0, aV0)
    MM2(5, afU1, afV1, aU1, aV1)
    MM2(6, afU1, afV1, aU2, aV2)
    MM2(7, afU1, afV1, aU3, aV3)
    #undef MM2

    __syncthreads();   // wbuf[jt&1] reads done; stage(jt+1) landed
  }

  // hoisted bias per gene quad
  float br0 = (0 * 32 + m < 117) ? b_reg[0 * 32 + m] : 0.f;
  float br1 = (1 * 32 + m < 117) ? b_reg[1 * 32 + m] : 0.f;
  float br2 = (2 * 32 + m < 117) ? b_reg[2 * 32 + m] : 0.f;
  float br3 = (3 * 32 + m < 117) ? b_reg[3 * 32 + m] : 0.f;

  // ---- epilogue: 8 passes of 64 cells through C[64][128] ----
  float part = 0.f;
  for (int p = 0; p < 8; ++p) {
    if (ct == p) {
      #define EPI(Q, ACC, NB, BR)                                          \
        {                                                                  \
          int g = (Q)*32 + m;                                              \
          _Pragma("unroll")                                                \
          for (int reg = 0; reg < 16; ++reg) {                             \
            int n = (NB) + (reg & 3) + 8 * (reg >> 2) + 4 * hh;            \
            C[n * 128 + g] = fmaxf(ACC[reg] + (BR) + gb, 0.f);             \
          }                                                                \
        }
      EPI(0, aU0, 0, br0) EPI(1, aU1, 0, br1)
      EPI(2, aU2, 0, br2) EPI(3, aU3, 0, br3)
      EPI(0, aV0, 32, br0) EPI(1, aV1, 32, br1)
      EPI(2, aV2, 32, br2) EPI(3, aV3, 32, br3)
      #undef EPI
    }
    __syncthreads();
    // read C into registers (coalesced layout decode)
    float cellreg[15];
    #pragma unroll
    for (int i = 0; i < 15; ++i) {
      int idx = i * 512 + tid;
      int n = idx / 117;
      int gg = idx - n * 117;
      cellreg[i] = (idx < 7488) ? C[n * 128 + gg] : 0.f;
    }
    // spot partials
    {
      int grp = tid >> 7, t = tid & 127;
      float s = 0.f;
      #pragma unroll
      for (int n = 0; n < 16; ++n) s += C[(grp * 16 + n) * 128 + t];
      red[grp * 128 + t] = s;
    }
    __syncthreads();
    if (tid < 128)
      part += red[tid] + red[128 + tid] + red[256 + tid] + red[384 + tid];
    // issue this pass's cell stores (drained by the NEXT pass's barrier)
    float* cellchunk = out + CELL_OUT_OFF + (rowbase + p * 64) * 117;
    #pragma unroll
    for (int i = 0; i < 15; ++i) {
      int idx = i * 512 + tid;
      if (idx < 7488) cellchunk[idx] = cellreg[i];
    }
  }
  if (tid < 117) out[SPOT_OUT_OFF + b * 117 + tid] = part;
}

extern "C" void kernel_launch(void* const* d_in, const int* in_sizes, int n_in,
                              void* d_out, int out_size, void* d_ws, size_t ws_size,
                              hipStream_t stream) {
  const float* images      = (const float*)d_in[0];
  const float* spot_images = (const float*)d_in[1];
  // d_in[2] = gene_expression (unused by the reference)
  const float* W_emph = (const float*)d_in[3];
  const float* b_emph = (const float*)d_in[4];
  const float* W_reg  = (const float*)d_in[5];
  const float* b_reg  = (const float*)d_in[6];
  const float* W_patch = (const float*)d_in[7];
  const float* b_patch = (const float*)d_in[8];
  const float* W_glob  = (const float*)d_in[9];
  const float* b_glob  = (const float*)d_in[10];
  float* out = (float*)d_out;

  unsigned short* wcomb = (unsigned short*)((char*)d_ws + WCOMB_OFF);
  float* glob  = (float*)((char*)d_ws + GLOB_OFF);

  prep_kernel<<<496, 128, 0, stream>>>(spot_images, W_patch, b_patch, W_glob,
                                       b_glob, W_reg, W_emph, b_emph, wcomb,
                                       glob);
  main_kernel<<<256, 512, 0, stream>>>(images, b_reg, wcomb, glob, out);
}

// Round 12
// 51.169 us; speedup vs baseline: 1.4603x; 1.0020x over previous
//
#include <hip/hip_runtime.h>

// B=256, N=512 cells, G=117 genes, CH=25 conv channels.
// One block = one batch (512 cells), grid 256 = 1 block/CU, 8 waves; wave owns
// 64 cells (U/V subtiles of 32) x all 128 genes. Conv-as-MFMA with register
// handoff (cvt_pk + permlane32_swap) into the regression MFMAs.
// BARRIER-MINIMAL: weights staged in two 120KB mega-slabs (10 jt each) into
// 155KB dynamic LDS -> inner 10-jt runs have ZERO barriers (waves drift,
// compiler pipelines across jt). Spot reduced in registers. Epilogue uses two
// 64KB ping-pong C buffers (128 cells/round, 4 barriers total).
// out1 streamed during the K loop; cell stores paced across epilogue rounds.

typedef __attribute__((ext_vector_type(16))) float f32x16;
typedef __attribute__((ext_vector_type(8))) short short8;
typedef __attribute__((ext_vector_type(2))) unsigned int uint2v;
typedef __attribute__((ext_vector_type(4))) unsigned int uint4v;

#define WCOMB_OFF 0          // 245760 B : [20 jt][12288 B = 4KB a | 8KB wb]
#define GLOB_OFF  245760     // 1024 B   : glob[256]

#define SPOT_OUT_OFF 0
#define CELL_OUT_OFF 29952
#define OUT1_OUT_OFF 15365376

#define SMEM_BYTES 155648    // imgbs 32768 + wslab 122880

__device__ __forceinline__ unsigned short f2bf(float x) {
  unsigned int u = __builtin_bit_cast(unsigned int, x);
  u = (u + 0x7FFFu + ((u >> 16) & 1u)) >> 16;   // RNE
  return (unsigned short)u;
}

__device__ __forceinline__ unsigned int cvt_pk_bf16(float lo, float hi) {
  unsigned int w;
  asm("v_cvt_pk_bf16_f32 %0, %1, %2" : "=v"(w) : "v"(lo), "v"(hi));
  return w;
}

__device__ __forceinline__ void gload16(const void* g, void* l) {
  __builtin_amdgcn_global_load_lds(
      (const __attribute__((address_space(1))) void*)g,
      (__attribute__((address_space(3))) void*)l, 16, 0, 0);
}

// blocks 0..255: glob ; 256..335: a-frags (jt x s) ; 336..495: wb (sg x q)
__global__ __launch_bounds__(128) void prep_kernel(
    const float* __restrict__ spot_images, const float* __restrict__ W_patch,
    const float* __restrict__ b_patch, const float* __restrict__ W_glob,
    const float* __restrict__ b_glob, const float* __restrict__ W_reg,
    const float* __restrict__ W_emph, const float* __restrict__ b_emph,
    unsigned short* __restrict__ wcomb, float* __restrict__ glob) {
  int bid = blockIdx.x;
  int tid = threadIdx.x;
  if (bid < 256) {
    __shared__ float red[75];
    if (tid < 75) {
      int token = tid / 3;
      int chan = tid - token * 3;
      int ty = token / 5, tx = token - ty * 5;
      const float* img = spot_images + bid * 784 + (ty * 5) * 28 + tx * 5;
      float a = 0.f;
      #pragma unroll
      for (int i = 0; i < 5; ++i)
        #pragma unroll
        for (int j = 0; j < 5; ++j)
          a = fmaf(img[i * 28 + j], W_patch[chan * 25 + i * 5 + j], a);
      a += b_patch[chan];
      red[tid] = a * W_glob[tid];
    }
    __syncthreads();
    if (tid == 0) {
      float s = b_glob[0];
      for (int k = 0; k < 75; ++k) s += red[k];
      glob[bid] = (s > 0.f) ? s : expm1f(s);
    }
  } else if (bid < 336) {
    int idx = bid - 256;               // jt*4 + s
    int jt = idx >> 2, s = idx & 3;
    if (tid < 64) {
      int j = jt * 32 + (tid & 31);
      int h = tid >> 5;
      unsigned short hv[8];
      #pragma unroll
      for (int jj = 0; jj < 8; ++jj) {
        int i = s * 16 + h * 8 + jj;
        float val = 0.f;
        if (j < 625) {
          int ch = j / 25, p = j % 25;
          int oy = p / 5, ox = p - oy * 5;
          if (i < 49) {
            int iy = i / 7, ix = i - iy * 7;
            int ky = iy - oy, kx = ix - ox;
            if (ky >= 0 && ky < 3 && kx >= 0 && kx < 3)
              val = W_emph[ch * 9 + ky * 3 + kx];
          } else if (i == 49) {
            val = b_emph[ch];
          }
        }
        hv[jj] = f2bf(val);
      }
      unsigned int u[4];
      #pragma unroll
      for (int k = 0; k < 4; ++k)
        u[k] = (unsigned int)hv[2 * k] | ((unsigned int)hv[2 * k + 1] << 16);
      ((uint4*)wcomb)[jt * 768 + s * 64 + tid] = make_uint4(u[0], u[1], u[2], u[3]);
    }
  } else {
    int idx = bid - 336;               // sg*4 + q   (sg = kstep 0..39)
    int sg = idx >> 2, q = idx & 3;
    if (tid < 64) {
      int g = q * 32 + (tid & 31);
      int h = tid >> 5;
      unsigned short hv[8];
      #pragma unroll
      for (int jj = 0; jj < 8; ++jj) {
        int k = sg * 16 + h * 8 + jj;
        float val = (g < 117 && k < 625) ? W_reg[g * 625 + k] : 0.f;
        hv[jj] = f2bf(val);
      }
      unsigned int u[4];
      #pragma unroll
      for (int k = 0; k < 4; ++k)
        u[k] = (unsigned int)hv[2 * k] | ((unsigned int)hv[2 * k + 1] << 16);
      int jt = sg >> 1, c = (sg & 1) * 4 + q;   // chunk c = ks*4 + q
      ((uint4*)wcomb)[jt * 768 + 256 + c * 64 + tid] =
          make_uint4(u[0], u[1], u[2], u[3]);
    }
  }
}

// One block = batch b (512 cells). 512 threads = 8 waves (ct = 64-cell group).
__global__ __launch_bounds__(512, 2) void main_kernel(
    const float* __restrict__ images, const float* __restrict__ b_reg,
    const unsigned short* __restrict__ wcomb, const float* __restrict__ glob,
    float* __restrict__ out) {
  extern __shared__ char smem[];
  unsigned short* imgbs = (unsigned short*)smem;  // 32768 B [8 kc][256 cell][8]
  char* wslab = smem + 32768;                     // 122880 B = 10 jt slabs
  float* C0 = (float*)smem;                       // 65536 B [128][128] (epi)
  float* C1 = (float*)(smem + 65536);             // 65536 B
  float* redp = (float*)(smem + 131072);          // 4096 B [8][128]
  int tid = threadIdx.x;
  int b = blockIdx.x;
  int l = tid & 63;
  int ct = __builtin_amdgcn_readfirstlane(tid >> 6);   // wave 0..7
  int m = l & 31, hh = l >> 5;
  const char* wcombB = (const char*)wcomb;
  const short8* imgb8 = (const short8*)imgbs;

  float gb = glob[b];
  size_t rowbase = (size_t)b * 512;
  float4 gv = make_float4(gb, gb, gb, gb);
  float4* o1v = (float4*)(out + OUT1_OUT_OFF + rowbase * 117);  // 14976 float4

  // stage 10 jt-slabs (120 KB) for half h: 120 wave-chunks of 1KB
  auto stage_half = [&](int h) {
    #pragma unroll
    for (int i = 0; i < 15; ++i) {
      int c = ct + 8 * i;
      gload16(wcombB + h * 122880 + c * 1024 + l * 16, wslab + c * 1024);
    }
  };

  // stage 256 cells (one half) of img -> bf16 chunk-major LDS
  auto stageimg = [&](int hf) {
    #pragma unroll
    for (int it = 0; it < 4; ++it) {
      int u = it * 512 + tid;
      int cell = u & 255, kc = u >> 8;
      const float* src =
          images + (size_t)(b * 512 + hf * 256 + cell) * 49 + kc * 8;
      float v[8];
      #pragma unroll
      for (int j = 0; j < 8; ++j) v[j] = 0.f;
      if (kc < 6) {
        #pragma unroll
        for (int j = 0; j < 8; ++j) v[j] = src[j];
      } else if (kc == 6) {
        v[0] = src[0];
        v[1] = 1.0f;
      }
      unsigned int uu[4];
      #pragma unroll
      for (int k = 0; k < 4; ++k) uu[k] = cvt_pk_bf16(v[2 * k], v[2 * k + 1]);
      ((uint4*)imgbs)[kc * 256 + cell] = make_uint4(uu[0], uu[1], uu[2], uu[3]);
    }
  };

  // persistent img B-frags: subtile U = cells ct*64+0..31, V = +32..63
  short8 bU0, bU1, bU2, bU3, bV0, bV1, bV2, bV3;
  int base = (ct & 3) * 64;   // local cell base within the half
  stageimg(0);
  __syncthreads();
  if (ct < 4) {
    bU0 = imgb8[(0 + hh) * 256 + base + m];
    bU1 = imgb8[(2 + hh) * 256 + base + m];
    bU2 = imgb8[(4 + hh) * 256 + base + m];
    bU3 = imgb8[(6 + hh) * 256 + base + m];
    bV0 = imgb8[(0 + hh) * 256 + base + 32 + m];
    bV1 = imgb8[(2 + hh) * 256 + base + 32 + m];
    bV2 = imgb8[(4 + hh) * 256 + base + 32 + m];
    bV3 = imgb8[(6 + hh) * 256 + base + 32 + m];
  }
  __syncthreads();
  stageimg(1);
  __syncthreads();
  if (ct >= 4) {
    bU0 = imgb8[(0 + hh) * 256 + base + m];
    bU1 = imgb8[(2 + hh) * 256 + base + m];
    bU2 = imgb8[(4 + hh) * 256 + base + m];
    bU3 = imgb8[(6 + hh) * 256 + base + m];
    bV0 = imgb8[(0 + hh) * 256 + base + 32 + m];
    bV1 = imgb8[(2 + hh) * 256 + base + 32 + m];
    bV2 = imgb8[(4 + hh) * 256 + base + 32 + m];
    bV3 = imgb8[(6 + hh) * 256 + base + 32 + m];
  }
  stage_half(0);
  __syncthreads();

  f32x16 aU0, aU1, aU2, aU3, aV0, aV1, aV2, aV3;
  #pragma unroll
  for (int i = 0; i < 16; ++i) {
    aU0[i] = 0.f; aU1[i] = 0.f; aU2[i] = 0.f; aU3[i] = 0.f;
    aV0[i] = 0.f; aV1[i] = 0.f; aV2[i] = 0.f; aV3[i] = 0.f;
  }

  auto body = [&](int jl, int jt) {
    if (jt < 15) {                              // out1 stream during compute
      int i0 = jt * 1024 + tid;
      o1v[i0] = gv;
      int i1 = i0 + 512;
      if (i1 < 14976) o1v[i1] = gv;
    }
    const short8* wB = (const short8*)(wslab + jl * 12288);
    short8 a0 = wB[l];
    short8 a1 = wB[64 + l];
    short8 a2 = wB[128 + l];
    short8 a3 = wB[192 + l];

    // conv U then pack
    f32x16 o;
    #pragma unroll
    for (int i = 0; i < 16; ++i) o[i] = 0.f;
    o = __builtin_amdgcn_mfma_f32_32x32x16_bf16(a0, bU0, o, 0, 0, 0);
    o = __builtin_amdgcn_mfma_f32_32x32x16_bf16(a1, bU1, o, 0, 0, 0);
    o = __builtin_amdgcn_mfma_f32_32x32x16_bf16(a2, bU2, o, 0, 0, 0);
    o = __builtin_amdgcn_mfma_f32_32x32x16_bf16(a3, bU3, o, 0, 0, 0);
    unsigned int W[8];
    #pragma unroll
    for (int q = 0; q < 8; ++q)
      W[q] = cvt_pk_bf16(fmaxf(o[2 * q], 0.f), fmaxf(o[2 * q + 1], 0.f));
    uint2v s02 = __builtin_amdgcn_permlane32_swap(W[0], W[2], false, false);
    uint2v s13 = __builtin_amdgcn_permlane32_swap(W[1], W[3], false, false);
    uint2v s46 = __builtin_amdgcn_permlane32_swap(W[4], W[6], false, false);
    uint2v s57 = __builtin_amdgcn_permlane32_swap(W[5], W[7], false, false);
    uint4v f0 = {s02[0], s13[0], s02[1], s13[1]};
    uint4v f1 = {s46[0], s57[0], s46[1], s57[1]};
    short8 afU0 = __builtin_bit_cast(short8, f0);
    short8 afU1 = __builtin_bit_cast(short8, f1);

    // conv V then pack
    #pragma unroll
    for (int i = 0; i < 16; ++i) o[i] = 0.f;
    o = __builtin_amdgcn_mfma_f32_32x32x16_bf16(a0, bV0, o, 0, 0, 0);
    o = __builtin_amdgcn_mfma_f32_32x32x16_bf16(a1, bV1, o, 0, 0, 0);
    o = __builtin_amdgcn_mfma_f32_32x32x16_bf16(a2, bV2, o, 0, 0, 0);
    o = __builtin_amdgcn_mfma_f32_32x32x16_bf16(a3, bV3, o, 0, 0, 0);
    #pragma unroll
    for (int q = 0; q < 8; ++q)
      W[q] = cvt_pk_bf16(fmaxf(o[2 * q], 0.f), fmaxf(o[2 * q + 1], 0.f));
    s02 = __builtin_amdgcn_permlane32_swap(W[0], W[2], false, false);
    s13 = __builtin_amdgcn_permlane32_swap(W[1], W[3], false, false);
    s46 = __builtin_amdgcn_permlane32_swap(W[4], W[6], false, false);
    s57 = __builtin_amdgcn_permlane32_swap(W[5], W[7], false, false);
    uint4v g0 = {s02[0], s13[0], s02[1], s13[1]};
    uint4v g1 = {s46[0], s57[0], s46[1], s57[1]};
    short8 afV0 = __builtin_bit_cast(short8, g0);
    short8 afV1 = __builtin_bit_cast(short8, g1);

    // mm2: each wb chunk read once, used for both U and V
    #define MM2(c, AFU, AFV, AU, AV)                                        \
      {                                                                     \
        short8 w = wB[256 + (c)*64 + l];                                    \
        AU = __builtin_amdgcn_mfma_f32_32x32x16_bf16(AFU, w, AU, 0, 0, 0);  \
        AV = __builtin_amdgcn_mfma_f32_32x32x16_bf16(AFV, w, AV, 0, 0, 0);  \
      }
    MM2(0, afU0, afV0, aU0, aV0)
    MM2(1, afU0, afV0, aU1, aV1)
    MM2(2, afU0, afV0, aU2, aV2)
    MM2(3, afU0, afV0, aU3, aV3)
    MM2(4, afU1, afV1, aU0, aV0)
    MM2(5, afU1, afV1, aU1, aV1)
    MM2(6, afU1, afV1, aU2, aV2)
    MM2(7, afU1, afV1, aU3, aV3)
    #undef MM2
  };

  for (int jl = 0; jl < 10; ++jl) body(jl, jl);          // no barriers inside
  __syncthreads();                                        // wslab reads done
  stage_half(1);
  __syncthreads();
  for (int jl = 0; jl < 10; ++jl) body(jl, 10 + jl);
  __syncthreads();                                        // loop fully done

  // hoisted bias per gene quad
  float br0 = (0 * 32 + m < 117) ? b_reg[0 * 32 + m] : 0.f;
  float br1 = (1 * 32 + m < 117) ? b_reg[1 * 32 + m] : 0.f;
  float br2 = (2 * 32 + m < 117) ? b_reg[2 * 32 + m] : 0.f;
  float br3 = (3 * 32 + m < 117) ? b_reg[3 * 32 + m] : 0.f;

  // ---- spot from registers: per quad, sum relu over this wave's 64 cells
  {
    auto rsum = [&](const f32x16& AU, const f32x16& AV, float br) {
      float s = 0.f;
      #pragma unroll
      for (int reg = 0; reg < 16; ++reg)
        s += fmaxf(AU[reg] + br + gb, 0.f) + fmaxf(AV[reg] + br + gb, 0.f);
      s += __shfl_xor(s, 32, 64);
      return s;
    };
    float s0 = rsum(aU0, aV0, br0);
    float s1 = rsum(aU1, aV1, br1);
    float s2 = rsum(aU2, aV2, br2);
    float s3 = rsum(aU3, aV3, br3);
    if (hh == 0) {
      redp[ct * 128 + m] = s0;
      redp[ct * 128 + 32 + m] = s1;
      redp[ct * 128 + 64 + m] = s2;
      redp[ct * 128 + 96 + m] = s3;
    }
  }

  // ---- epilogue: 4 rounds of 128 cells, ping-pong C0/C1 ----
  #define EPI(Cb, Q, ACC, NB, BR)                                          \
    {                                                                      \
      int g = (Q)*32 + m;                                                  \
      _Pragma("unroll")                                                    \
      for (int reg = 0; reg < 16; ++reg) {                                 \
        int n = (NB) + (reg & 3) + 8 * (reg >> 2) + 4 * hh;                \
        (Cb)[n * 128 + g] = fmaxf(ACC[reg] + (BR) + gb, 0.f);              \
      }                                                                    \
    }
  #define EPIW(Cb, e)                                                      \
    {                                                                      \
      int nb = (e)*64;                                                     \
      EPI(Cb, 0, aU0, nb, br0) EPI(Cb, 1, aU1, nb, br1)                    \
      EPI(Cb, 2, aU2, nb, br2) EPI(Cb, 3, aU3, nb, br3)                    \
      EPI(Cb, 0, aV0, nb + 32, br0) EPI(Cb, 1, aV1, nb + 32, br1)          \
      EPI(Cb, 2, aV2, nb + 32, br2) EPI(Cb, 3, aV3, nb + 32, br3)          \
    }
  auto streamC = [&](const float* Cb, int r) {
    float* cellchunk = out + CELL_OUT_OFF + (rowbase + r * 128) * 117;
    #pragma unroll
    for (int i = 0; i < 30; ++i) {
      int idx = i * 512 + tid;
      if (idx < 14976) {
        int n = idx / 117;
        int gg = idx - n * 117;
        cellchunk[idx] = Cb[n * 128 + gg];
      }
    }
  };

  // round 0 written by waves 0,1
  if (ct < 2) EPIW(C0, ct & 1);
  __syncthreads();
  // spot finalize (redp stable from here on)
  if (tid < 117) {
    float s = 0.f;
    #pragma unroll
    for (int w = 0; w < 8; ++w) s += redp[w * 128 + tid];
    out[SPOT_OUT_OFF + b * 117 + tid] = s;
  }
  if (ct == 2 || ct == 3) EPIW(C1, ct & 1);   // round 1
  streamC(C0, 0);
  __syncthreads();
  if (ct == 4 || ct == 5) EPIW(C0, ct & 1);   // round 2
  streamC(C1, 1);
  __syncthreads();
  if (ct == 6 || ct == 7) EPIW(C1, ct & 1);   // round 3
  streamC(C0, 2);
  __syncthreads();
  streamC(C1, 3);
  #undef EPIW
  #undef EPI
}

extern "C" void kernel_launch(void* const* d_in, const int* in_sizes, int n_in,
                              void* d_out, int out_size, void* d_ws, size_t ws_size,
                              hipStream_t stream) {
  const float* images      = (const float*)d_in[0];
  const float* spot_images = (const float*)d_in[1];
  // d_in[2] = gene_expression (unused by the reference)
  const float* W_emph = (const float*)d_in[3];
  const float* b_emph = (const float*)d_in[4];
  const float* W_reg  = (const float*)d_in[5];
  const float* b_reg  = (const float*)d_in[6];
  const float* W_patch = (const float*)d_in[7];
  const float* b_patch = (const float*)d_in[8];
  const float* W_glob  = (const float*)d_in[9];
  const float* b_glob  = (const float*)d_in[10];
  float* out = (float*)d_out;

  unsigned short* wcomb = (unsigned short*)((char*)d_ws + WCOMB_OFF);
  float* glob  = (float*)((char*)d_ws + GLOB_OFF);

  (void)hipFuncSetAttribute((const void*)main_kernel,
                            hipFuncAttributeMaxDynamicSharedMemorySize,
                            SMEM_BYTES);

  prep_kernel<<<496, 128, 0, stream>>>(spot_images, W_patch, b_patch, W_glob,
                                       b_glob, W_reg, W_emph, b_emph, wcomb,
                                       glob);
  main_kernel<<<256, 512, SMEM_BYTES, stream>>>(images, b_reg, wcomb, glob,
                                                out);
}